// Round 17
// baseline (2243.218 us; speedup 1.0000x reference)
//
#include <hip/hip_runtime.h>
#include <math.h>

// ---------------- problem constants ----------------
constexpr int B  = 2;
constexpr int S  = 4096;
constexpr int H  = 768;
constexpr int NH = 12;
constexpr int FF = 3072;
constexpr int L  = 4;
constexpr int R  = 3;
constexpr int NB = 64;
constexpr int AB = 8;            // 3 window + 2 global + 3 random
constexpr float SCALE = 0.125f;  // 1/sqrt(64)
constexpr int QKV_N = 3 * H;     // 2304

constexpr int ROWS = B * S;                  // 8192
constexpr size_t XSZ = (size_t)B * S * H;    // 6291456

typedef short bf16x8 __attribute__((ext_vector_type(8)));
typedef unsigned short u16x8 __attribute__((ext_vector_type(8)));
typedef unsigned short u16x4 __attribute__((ext_vector_type(4)));
typedef float f32x4 __attribute__((ext_vector_type(4)));
typedef unsigned short ushort_t;

// fp32 -> bf16 round-nearest-even
__device__ __forceinline__ ushort_t f2b(float f) {
  union { float f; unsigned u; } c; c.f = f;
  unsigned r = c.u + 0x7fffu + ((c.u >> 16) & 1u);
  return (ushort_t)(r >> 16);
}
__device__ __forceinline__ float b2f(ushort_t u) {
  union { float f; unsigned u; } c; c.u = ((unsigned)u) << 16;
  return c.f;
}

// gelu, tanh approximation (max abs dev from exact erf-gelu ~1e-3)
__device__ __forceinline__ float gelu_f(float x) {
  float y = 0.7978845608f * x * (1.0f + 0.044715f * x * x);
  float e = __expf(2.0f * y);
  float th = 1.0f - 2.0f / (e + 1.0f);   // tanh(y)
  return 0.5f * x * (1.0f + th);
}

__device__ __forceinline__ void gload16(const void* g, void* l) {
  __builtin_amdgcn_global_load_lds(
      (const __attribute__((address_space(1))) unsigned int*)g,
      (__attribute__((address_space(3))) unsigned int*)l, 16, 0, 0);
}

// DPP cross-lane move within 16-lane rows (VALU pipe, no LDS round-trip)
template <int CTRL>
__device__ __forceinline__ float dppmv(float x) {
  union { float f; int i; } c; c.f = x;
  c.i = __builtin_amdgcn_update_dpp(c.i, c.i, CTRL, 0xF, 0xF, true);
  return c.f;
}
__device__ __forceinline__ float redmax16(float x) {
  x = fmaxf(x, dppmv<0xB1>(x));
  x = fmaxf(x, dppmv<0x4E>(x));
  x = fmaxf(x, dppmv<0x124>(x));
  x = fmaxf(x, dppmv<0x128>(x));
  return x;
}
__device__ __forceinline__ float redsum16(float x) {
  x += dppmv<0xB1>(x);
  x += dppmv<0x4E>(x);
  x += dppmv<0x124>(x);
  x += dppmv<0x128>(x);
  return x;
}

// ---------------- embedding: bf16 x out, u16x4 vectorized ----------------
__global__ __launch_bounds__(256) void embed_kernel(
    const float* __restrict__ ids, const float* __restrict__ w,
    const float* __restrict__ bvec, ushort_t* __restrict__ x) {
  int idx = blockIdx.x * 256 + threadIdx.x;           // group of 4 channels
  if (idx >= (int)(XSZ / 4)) return;
  int bs = idx / (H / 4);
  int hc = (idx % (H / 4)) * 4;
  f32x4 s = *(const f32x4*)&bvec[hc];
  #pragma unroll
  for (int k = 0; k < 4; ++k) {
    float id = ids[bs * 4 + k];
    f32x4 wv = *(const f32x4*)&w[k * H + hc];
    #pragma unroll
    for (int j = 0; j < 4; ++j) s[j] += id * wv[j];
  }
  u16x4 pk;
  #pragma unroll
  for (int j = 0; j < 4; ++j) pk[j] = f2b(s[j]);
  *(u16x4*)&x[(size_t)bs * H + hc] = pk;
}

// ---------------- layernorm: wave-per-row, u16x4 vectorized ----------------
__global__ __launch_bounds__(256) void ln_kernel(
    const ushort_t* __restrict__ x, const float* __restrict__ g,
    const float* __restrict__ bvec, ushort_t* __restrict__ out) {
  const int wave = threadIdx.x >> 6, lane = threadIdx.x & 63;
  const int row = blockIdx.x * 4 + wave;
  const ushort_t* xr = x + (size_t)row * H;
  float v[12];
  #pragma unroll
  for (int j = 0; j < 3; ++j) {
    u16x4 a = *(const u16x4*)&xr[lane * 4 + j * 256];
    #pragma unroll
    for (int q = 0; q < 4; ++q) v[j * 4 + q] = b2f(a[q]);
  }
  float s = 0.f, ss = 0.f;
  #pragma unroll
  for (int i = 0; i < 12; ++i) { s += v[i]; ss += v[i] * v[i]; }
  for (int off = 1; off < 64; off <<= 1) {
    s  += __shfl_xor(s,  off);
    ss += __shfl_xor(ss, off);
  }
  float mean = s * (1.0f / H);
  float var  = ss * (1.0f / H) - mean * mean;
  float rstd = rsqrtf(var + 1e-12f);
  ushort_t* orow = out + (size_t)row * H;
  #pragma unroll
  for (int j = 0; j < 3; ++j) {
    f32x4 gv = *(const f32x4*)&g[lane * 4 + j * 256];
    f32x4 bv = *(const f32x4*)&bvec[lane * 4 + j * 256];
    u16x4 pk;
    #pragma unroll
    for (int q = 0; q < 4; ++q)
      pk[q] = f2b((v[j * 4 + q] - mean) * rstd * gv[q] + bv[q]);
    *(u16x4*)&orow[lane * 4 + j * 256] = pk;
  }
}

// ---------------- weight transpose + fp32->bf16 ----------------
__global__ __launch_bounds__(256) void tcvt_kernel(
    const float* __restrict__ in, ushort_t* __restrict__ out,
    int K, int N, size_t inZ, size_t outZ) {
  __shared__ float tile[32][33];
  const float* inz = in + blockIdx.z * inZ;
  ushort_t* outz = out + blockIdx.z * outZ;
  int k0 = blockIdx.y * 32, n0 = blockIdx.x * 32;
  int tx = threadIdx.x & 31, ty = threadIdx.x >> 5;
  #pragma unroll
  for (int i = 0; i < 4; ++i) {
    int kk = ty + i * 8;
    tile[kk][tx] = inz[(size_t)(k0 + kk) * N + n0 + tx];
  }
  __syncthreads();
  #pragma unroll
  for (int i = 0; i < 4; ++i) {
    int nn = ty + i * 8;
    outz[(size_t)(n0 + nn) * K + k0 + tx] = f2b(tile[tx][nn]);
  }
}

__global__ __launch_bounds__(256) void concat_bias_kernel(
    const float* __restrict__ bq, const float* __restrict__ bk,
    const float* __restrict__ bv, float* __restrict__ out) {
  int i = blockIdx.x * 256 + threadIdx.x;
  if (i >= L * QKV_N) return;
  int l = i / QKV_N, c = i % QKV_N;
  float val = (c < H) ? bq[l * H + c] : (c < 2 * H) ? bk[l * H + c - H] : bv[l * H + c - 2 * H];
  out[i] = val;
}

// ============================================================================
// 128 x BN bf16 MFMA GEMM: 2 LDS buffers (depth-1 prefetch), single barrier
// per K-step, unroll-by-2 for immediate LDS offsets. N-FASTEST tile order.
// Occupancy over depth (m97/m103 structure): BN=256 -> 48 KB -> 3 blocks/CU
// (capacity 768 fits FFN1's grid 768 and QKV's 576 in ONE round; the old
// 3-buffer 72 KB variant capped capacity at 512 -> FFN1 ran 1.5 rounds).
// vmcnt(0) at step start waits for a tile issued a full step (~1200 cy of
// MFMA) earlier -> latency already covered; residual stall hidden by the
// co-resident blocks (m114 wave-level overlap).
// ============================================================================
// EPI: 0 = bias -> bf16 (+ vT for bn>=1536), 1 = bias + residual(bf16) -> bf16,
//      2 = bias + gelu -> bf16
template <int BN, int EPI>
__global__ __launch_bounds__(256, (BN == 256 ? 3 : 4)) void bgemm(
    const ushort_t* __restrict__ A, const ushort_t* __restrict__ Wt,
    const float* __restrict__ bias, const ushort_t* __restrict__ res,
    ushort_t* __restrict__ Cb, ushort_t* __restrict__ Cv,
    int M, int N, int K, int ncol) {
  constexpr int LDSB = (128 + BN) * 32;   // elems per buffer
  constexpr int NLD  = (128 + BN) / 64;   // gload sweeps per thread per K-tile
  constexpr int NI   = BN / 32;           // B-fragments per wave
  __shared__ ushort_t lds[2 * LDSB];

  // T1: bijective XCD swizzle (m204), N-fastest tile mapping
  const int nwg = (int)gridDim.x;
  const int qq = nwg >> 3, r0 = nwg & 7;
  const int xcd = (int)blockIdx.x & 7, loc = (int)blockIdx.x >> 3;
  const int swz = (xcd < r0 ? xcd * (qq + 1) : r0 * (qq + 1) + (xcd - r0) * qq) + loc;
  const int bm = (swz / ncol) * 128, bn = (swz % ncol) * BN;

  const int t = threadIdx.x;
  const int wid = t >> 6, lane = t & 63;
  const int fcol = lane & 15, fgrp = lane >> 4;
  const int wm = wid >> 1, wn = wid & 1;

  const ushort_t* src[NLD];
  int dst[NLD];
  #pragma unroll
  for (int j = 0; j < NLD; ++j) {
    int idx = j * 2048 + t * 8;
    dst[j] = idx;
    int ch = (idx >> 3) & 3;
    int row;
    const ushort_t* base;
    if (idx < 4096) { row = idx >> 5;           base = A  + (size_t)(bm + row) * K; }
    else            { row = (idx - 4096) >> 5;  base = Wt + (size_t)(bn + row) * K; }
    src[j] = base + ((ch ^ ((row >> 1) & 3)) << 3);
  }

  int aoff[4], boff[NI];
  #pragma unroll
  for (int mi = 0; mi < 4; ++mi) {
    int row = wm * 64 + mi * 16 + fcol;
    aoff[mi] = row * 32 + ((fgrp ^ ((row >> 1) & 3)) << 3);
  }
  #pragma unroll
  for (int ni = 0; ni < NI; ++ni) {
    int row = wn * (BN / 2) + ni * 16 + fcol;
    boff[ni] = 4096 + row * 32 + ((fgrp ^ ((row >> 1) & 3)) << 3);
  }

  f32x4 acc[4][NI] = {};

  // prologue: tile 0 -> buf0
  #pragma unroll
  for (int j = 0; j < NLD; ++j) gload16(src[j], &lds[dst[j]]);
  int kgl = 32;

// STEP(P, DOSTAGE): wait tile P landed -> barrier (also orders prior reads
// of buf[P^1] before this step's stage into it) -> stage tile tau+1 ->
// ds_read buf[P] -> MFMA.
#define GEMM_STEP(P, DOSTAGE)                                              \
  {                                                                        \
    asm volatile("s_waitcnt vmcnt(0)" ::: "memory");                       \
    __builtin_amdgcn_sched_barrier(0);                                     \
    __builtin_amdgcn_s_barrier();                                          \
    __builtin_amdgcn_sched_barrier(0);                                     \
    if (DOSTAGE) {                                                         \
      _Pragma("unroll")                                                    \
      for (int j = 0; j < NLD; ++j)                                        \
        gload16(src[j] + kgl, &lds[((P) ^ 1) * LDSB + dst[j]]);            \
      kgl += 32;                                                           \
    }                                                                      \
    bf16x8 af[4], bfr[NI];                                                 \
    _Pragma("unroll")                                                      \
    for (int mi = 0; mi < 4; ++mi)                                         \
      af[mi] = *(const bf16x8*)&lds[(P) * LDSB + aoff[mi]];                \
    _Pragma("unroll")                                                      \
    for (int ni = 0; ni < NI; ++ni)                                        \
      bfr[ni] = *(const bf16x8*)&lds[(P) * LDSB + boff[ni]];               \
    __builtin_amdgcn_s_setprio(1);                                         \
    _Pragma("unroll")                                                      \
    for (int mi = 0; mi < 4; ++mi)                                         \
      _Pragma("unroll")                                                    \
      for (int ni = 0; ni < NI; ++ni)                                      \
        acc[mi][ni] = __builtin_amdgcn_mfma_f32_16x16x32_bf16(             \
            af[mi], bfr[ni], acc[mi][ni], 0, 0, 0);                        \
    __builtin_amdgcn_s_setprio(0);                                         \
  }

  const int NT = K >> 5;   // 24 or 96, even
  for (int tau = 0; tau < NT - 2; tau += 2) {
    GEMM_STEP(0, true)
    GEMM_STEP(1, true)
  }
  GEMM_STEP(0, true)    // tau = NT-2: stages tile NT-1 -> buf1
  GEMM_STEP(1, false)   // tau = NT-1
#undef GEMM_STEP

  // epilogue (m = ..+fgrp*4+r, n = ..+fcol)
  if (EPI == 0 && bn >= 2 * H) {
    // V block-columns -> transposed vT[c][m], 8-B packed stores (m-quad)
    #pragma unroll
    for (int mi = 0; mi < 4; ++mi) {
      const int m = bm + wm * 64 + mi * 16 + fgrp * 4;
      #pragma unroll
      for (int ni = 0; ni < NI; ++ni) {
        const int n = bn + wn * (BN / 2) + ni * 16 + fcol;
        const float bb = bias[n];
        u16x4 pk;
        #pragma unroll
        for (int r = 0; r < 4; ++r) pk[r] = f2b(acc[mi][ni][r] + bb);
        *(u16x4*)&Cv[(size_t)(n - 2 * H) * M + m] = pk;
      }
    }
    return;
  }
  #pragma unroll
  for (int mi = 0; mi < 4; ++mi) {
    const int m = bm + wm * 64 + mi * 16 + fgrp * 4;
    #pragma unroll
    for (int ni = 0; ni < NI; ++ni) {
      const int n = bn + wn * (BN / 2) + ni * 16 + fcol;
      const float bb = bias[n];
      #pragma unroll
      for (int r = 0; r < 4; ++r) {
        float val = acc[mi][ni][r] + bb;
        if (EPI == 1) {
          val += b2f(res[(size_t)(m + r) * N + n]);
          Cb[(size_t)(m + r) * N + n] = f2b(val);
        } else if (EPI == 2) {
          Cb[(size_t)(m + r) * N + n] = f2b(gelu_f(val));
        } else {
          Cb[(size_t)(m + r) * N + n] = f2b(val);
        }
      }
    }
  }
}

// ---------------- BigBird sparse attention, bf16 MFMA flash-style -----------
__global__ __launch_bounds__(256) void attn_mfma(
    const ushort_t* __restrict__ qkv, const ushort_t* __restrict__ vT,
    const int* __restrict__ rb, ushort_t* __restrict__ ao) {
  __shared__ ushort_t Ks[2][64 * 72];
  __shared__ ushort_t Vt[2][64 * 72];
  __shared__ ushort_t Ps[4][16 * 72];
  const int xb = blockIdx.x;
  const int n = ((xb & 7) << 3) | (xb >> 3);   // bijective on 0..63
  const int hh = blockIdx.y, b = blockIdx.z;
  const int t = threadIdx.x;
  const int wid = t >> 6, lane = t & 63;
  const int fcol = lane & 15, fgrp = lane >> 4;
  const int qr0 = n * 64 + wid * 16;

  bf16x8 qf[2];
  #pragma unroll
  for (int kc = 0; kc < 2; ++kc)
    qf[kc] = *(const bf16x8*)&qkv[((size_t)(b * S) + qr0 + fcol) * QKV_N + hh * 64 + kc * 32 + fgrp * 8];

  f32x4 oacc[4] = {};
  float mrow[4], lrow[4];
  #pragma unroll
  for (int r = 0; r < 4; ++r) { mrow[r] = -1e30f; lrow[r] = 0.f; }

  int kbs[AB];
  kbs[0] = (n > 0) ? n - 1 : 0;
  kbs[1] = n;
  kbs[2] = (n < NB - 1) ? n + 1 : NB - 1;
  kbs[3] = 0;
  kbs[4] = NB - 1;
  kbs[5] = rb[n * R + 0];
  kbs[6] = rb[n * R + 1];
  kbs[7] = rb[n * R + 2];

  const ushort_t* kbase = qkv + (size_t)(b * S) * QKV_N + H + hh * 64;
  const ushort_t* vbase = vT + (size_t)(hh * 64) * ROWS + b * S;

  const int srow = t >> 3;
  const int soff = (t & 7) * 8;

  {
    const int kb = kbs[0];
    u16x8 k0 = *(const u16x8*)&kbase[(size_t)(kb * 64 + srow) * QKV_N + soff];
    u16x8 k1 = *(const u16x8*)&kbase[(size_t)(kb * 64 + srow + 32) * QKV_N + soff];
    u16x8 v0 = *(const u16x8*)&vbase[(size_t)srow * ROWS + kb * 64 + soff];
    u16x8 v1 = *(const u16x8*)&vbase[(size_t)(srow + 32) * ROWS + kb * 64 + soff];
    *(u16x8*)&Ks[0][srow * 72 + soff]        = k0;
    *(u16x8*)&Ks[0][(srow + 32) * 72 + soff] = k1;
    *(u16x8*)&Vt[0][srow * 72 + soff]        = v0;
    *(u16x8*)&Vt[0][(srow + 32) * 72 + soff] = v1;
  }
  __syncthreads();

  for (int a = 0; a < AB; ++a) {
    const int buf = a & 1;

    u16x8 pk0, pk1, pv0, pv1;
    if (a + 1 < AB) {
      const int kb = kbs[a + 1];
      pk0 = *(const u16x8*)&kbase[(size_t)(kb * 64 + srow) * QKV_N + soff];
      pk1 = *(const u16x8*)&kbase[(size_t)(kb * 64 + srow + 32) * QKV_N + soff];
      pv0 = *(const u16x8*)&vbase[(size_t)srow * ROWS + kb * 64 + soff];
      pv1 = *(const u16x8*)&vbase[(size_t)(srow + 32) * ROWS + kb * 64 + soff];
    }

    f32x4 sacc[4] = {};
    __builtin_amdgcn_s_setprio(1);
    #pragma unroll
    for (int ni = 0; ni < 4; ++ni)
      #pragma unroll
      for (int kc = 0; kc < 2; ++kc) {
        bf16x8 kf = *(const bf16x8*)&Ks[buf][(ni * 16 + fcol) * 72 + kc * 32 + fgrp * 8];
        sacc[ni] = __builtin_amdgcn_mfma_f32_16x16x32_bf16(qf[kc], kf, sacc[ni], 0, 0, 0);
      }
    __builtin_amdgcn_s_setprio(0);

    // online softmax: DPP 16-lane reduces
    #pragma unroll
    for (int ni = 0; ni < 4; ++ni)
      #pragma unroll
      for (int r = 0; r < 4; ++r) sacc[ni][r] *= SCALE;
    #pragma unroll
    for (int r = 0; r < 4; ++r) {
      float tm = fmaxf(fmaxf(sacc[0][r], sacc[1][r]), fmaxf(sacc[2][r], sacc[3][r]));
      tm = redmax16(tm);
      float mn = fmaxf(mrow[r], tm);
      float corr = __expf(mrow[r] - mn);
      mrow[r] = mn;
      float rs = 0.f;
      #pragma unroll
      for (int ni = 0; ni < 4; ++ni) {
        float p = __expf(sacc[ni][r] - mn);
        sacc[ni][r] = p;
        rs += p;
      }
      rs = redsum16(rs);
      lrow[r] = lrow[r] * corr + rs;
      #pragma unroll
      for (int ni = 0; ni < 4; ++ni) oacc[ni][r] *= corr;
    }

    if (a + 1 < AB) {
      *(u16x8*)&Ks[buf ^ 1][srow * 72 + soff]        = pk0;
      *(u16x8*)&Ks[buf ^ 1][(srow + 32) * 72 + soff] = pk1;
      *(u16x8*)&Vt[buf ^ 1][srow * 72 + soff]        = pv0;
      *(u16x8*)&Vt[buf ^ 1][(srow + 32) * 72 + soff] = pv1;
    }

    #pragma unroll
    for (int ni = 0; ni < 4; ++ni)
      #pragma unroll
      for (int r = 0; r < 4; ++r)
        Ps[wid][(fgrp * 4 + r) * 72 + ni * 16 + fcol] = f2b(sacc[ni][r]);

    bf16x8 pa[2];
    #pragma unroll
    for (int kc = 0; kc < 2; ++kc)
      pa[kc] = *(const bf16x8*)&Ps[wid][fcol * 72 + kc * 32 + fgrp * 8];

    __builtin_amdgcn_s_setprio(1);
    #pragma unroll
    for (int kc = 0; kc < 2; ++kc)
      #pragma unroll
      for (int ni = 0; ni < 4; ++ni) {
        bf16x8 vb = *(const bf16x8*)&Vt[buf][(ni * 16 + fcol) * 72 + kc * 32 + fgrp * 8];
        oacc[ni] = __builtin_amdgcn_mfma_f32_16x16x32_bf16(pa[kc], vb, oacc[ni], 0, 0, 0);
      }
    __builtin_amdgcn_s_setprio(0);

    __syncthreads();
  }

  #pragma unroll
  for (int r = 0; r < 4; ++r) {
    float inv = 1.0f / lrow[r];
    int row = qr0 + fgrp * 4 + r;
    #pragma unroll
    for (int ni = 0; ni < 4; ++ni)
      ao[((size_t)(b * S) + row) * H + hh * 64 + ni * 16 + fcol] = f2b(oacc[ni][r] * inv);
  }
}

// ---------------- classifier: bf16 x in, vectorized ----------------
__global__ __launch_bounds__(64) void clf_kernel(
    const ushort_t* __restrict__ x, const float* __restrict__ w,
    const float* __restrict__ bvec, float* __restrict__ out) {
  int row = blockIdx.x;
  int lane = threadIdx.x;
  const ushort_t* xr = x + (size_t)row * H;
  f32x4 p = {0.f, 0.f, 0.f, 0.f};
  #pragma unroll
  for (int j = 0; j < 3; ++j) {
    u16x4 xv4 = *(const u16x4*)&xr[lane * 4 + j * 256];
    #pragma unroll
    for (int q = 0; q < 4; ++q) {
      float xv = b2f(xv4[q]);
      f32x4 wv = *(const f32x4*)&w[(lane * 4 + j * 256 + q) * 4];
      #pragma unroll
      for (int c = 0; c < 4; ++c) p[c] += xv * wv[c];
    }
  }
  #pragma unroll
  for (int c = 0; c < 4; ++c)
    for (int off = 1; off < 64; off <<= 1) p[c] += __shfl_xor(p[c], off);
  if (lane == 0) {
    float l0 = p[0] + bvec[0], l1 = p[1] + bvec[1], l2 = p[2] + bvec[2], l3 = p[3] + bvec[3];
    float mx = fmaxf(fmaxf(l0, l1), fmaxf(l2, l3));
    float e0 = __expf(l0 - mx), e1 = __expf(l1 - mx), e2 = __expf(l2 - mx), e3 = __expf(l3 - mx);
    float inv = 1.0f / (e0 + e1 + e2 + e3);
    out[row * 4 + 0] = e0 * inv;
    out[row * 4 + 1] = e1 * inv;
    out[row * 4 + 2] = e2 * inv;
    out[row * 4 + 3] = e3 * inv;
  }
}

// ---------------- driver ----------------
extern "C" void kernel_launch(void* const* d_in, const int* in_sizes, int n_in,
                              void* d_out, int out_size, void* d_ws, size_t ws_size,
                              hipStream_t stream) {
  const float* input_ids = (const float*)d_in[0];
  const int*   rand_bl   = (const int*)  d_in[1];
  const float* emb_w = (const float*)d_in[2];
  const float* emb_b = (const float*)d_in[3];
  const float* ln1_g = (const float*)d_in[4];
  const float* ln1_b = (const float*)d_in[5];
  const float* wq = (const float*)d_in[6];
  const float* bq = (const float*)d_in[7];
  const float* wk = (const float*)d_in[8];
  const float* bk = (const float*)d_in[9];
  const float* wv = (const float*)d_in[10];
  const float* bv = (const float*)d_in[11];
  const float* wo = (const float*)d_in[12];
  const float* bo = (const float*)d_in[13];
  const float* ln2_g = (const float*)d_in[14];
  const float* ln2_b = (const float*)d_in[15];
  const float* w1 = (const float*)d_in[16];
  const float* b1 = (const float*)d_in[17];
  const float* w2 = (const float*)d_in[18];
  const float* b2 = (const float*)d_in[19];
  const float* clf_w = (const float*)d_in[20];
  const float* clf_b = (const float*)d_in[21];

  char* p = (char*)d_ws;
  ushort_t* x    = (ushort_t*)p; p += XSZ * 2;           // bf16 residual stream
  ushort_t* h    = (ushort_t*)p; p += XSZ * 2;
  ushort_t* qkv  = (ushort_t*)p; p += (size_t)ROWS * QKV_N * 2;
  ushort_t* ao   = (ushort_t*)p; p += XSZ * 2;
  ushort_t* ff   = qkv;  // [ROWS][FF] aliases qkv+ao (dead when FFN runs)
  ushort_t* vT   = (ushort_t*)p; p += (size_t)H * ROWS * 2;   // V^T [H][ROWS]
  ushort_t* qkvT = (ushort_t*)p; p += (size_t)L * QKV_N * H * 2;
  ushort_t* woT  = (ushort_t*)p; p += (size_t)L * H * H * 2;
  ushort_t* w1T  = (ushort_t*)p; p += (size_t)L * H * FF * 2;
  ushort_t* w2T  = (ushort_t*)p; p += (size_t)L * FF * H * 2;
  float*    bqkv = (float*)p;    p += (size_t)L * QKV_N * 4;

  // ---- weight prep ----
  tcvt_kernel<<<dim3(H / 32, H / 32, L), 256, 0, stream>>>(
      wq, qkvT + 0 * H * H, H, H, (size_t)H * H, (size_t)QKV_N * H);
  tcvt_kernel<<<dim3(H / 32, H / 32, L), 256, 0, stream>>>(
      wk, qkvT + 1 * H * H, H, H, (size_t)H * H, (size_t)QKV_N * H);
  tcvt_kernel<<<dim3(H / 32, H / 32, L), 256, 0, stream>>>(
      wv, qkvT + 2 * H * H, H, H, (size_t)H * H, (size_t)QKV_N * H);
  tcvt_kernel<<<dim3(H / 32, H / 32, L), 256, 0, stream>>>(
      wo, woT, H, H, (size_t)H * H, (size_t)H * H);
  tcvt_kernel<<<dim3(FF / 32, H / 32, L), 256, 0, stream>>>(
      w1, w1T, H, FF, (size_t)H * FF, (size_t)H * FF);
  tcvt_kernel<<<dim3(H / 32, FF / 32, L), 256, 0, stream>>>(
      w2, w2T, FF, H, (size_t)FF * H, (size_t)FF * H);
  concat_bias_kernel<<<(L * QKV_N + 255) / 256, 256, 0, stream>>>(bq, bk, bv, bqkv);

  embed_kernel<<<(int)((XSZ / 4 + 255) / 256), 256, 0, stream>>>(input_ids, emb_w, emb_b, x);

  for (int l = 0; l < L; ++l) {
    ln_kernel<<<ROWS / 4, 256, 0, stream>>>(x, ln1_g + l * H, ln1_b + l * H, h);

    // QKV: M=8192, N=2304, K=768 -> BN=256, grid 576 (3/CU -> one round)
    bgemm<256, 0><<<(ROWS / 128) * (QKV_N / 256), 256, 0, stream>>>(
        h, qkvT + (size_t)l * QKV_N * H, bqkv + l * QKV_N, nullptr,
        qkv, vT, ROWS, QKV_N, H, QKV_N / 256);

    attn_mfma<<<dim3(NB, NH, B), 256, 0, stream>>>(qkv, vT, rand_bl, ao);

    // O-proj: M=8192, N=768, K=768 -> BN=128, grid 384, residual bf16
    bgemm<128, 1><<<(ROWS / 128) * (H / 128), 256, 0, stream>>>(
        ao, woT + (size_t)l * H * H, bo + l * H, x, x, nullptr, ROWS, H, H, H / 128);

    ln_kernel<<<ROWS / 4, 256, 0, stream>>>(x, ln2_g + l * H, ln2_b + l * H, h);

    // FFN1: M=8192, N=3072, K=768 -> BN=256, grid 768 (3/CU -> one round)
    bgemm<256, 2><<<(ROWS / 128) * (FF / 256), 256, 0, stream>>>(
        h, w1T + (size_t)l * H * FF, b1 + l * FF, nullptr,
        ff, nullptr, ROWS, FF, H, FF / 256);

    // FFN2: M=8192, N=768, K=3072 -> BN=128, grid 384, residual bf16
    bgemm<128, 1><<<(ROWS / 128) * (H / 128), 256, 0, stream>>>(
        ff, w2T + (size_t)l * FF * H, b2 + l * H, x, x, nullptr, ROWS, H, FF, H / 128);
  }

  clf_kernel<<<ROWS, 64, 0, stream>>>(x, clf_w, clf_b, (float*)d_out);
}

// Round 18
// 943.688 us; speedup vs baseline: 2.3771x; 2.3771x over previous
//
#include <hip/hip_runtime.h>
#include <math.h>

// ---------------- problem constants ----------------
constexpr int B  = 2;
constexpr int S  = 4096;
constexpr int H  = 768;
constexpr int NH = 12;
constexpr int FF = 3072;
constexpr int L  = 4;
constexpr int R  = 3;
constexpr int NB = 64;
constexpr int AB = 8;            // 3 window + 2 global + 3 random
constexpr float SCALE = 0.125f;  // 1/sqrt(64)
constexpr int QKV_N = 3 * H;     // 2304

constexpr int ROWS = B * S;                  // 8192
constexpr size_t XSZ = (size_t)B * S * H;    // 6291456

typedef short bf16x8 __attribute__((ext_vector_type(8)));
typedef unsigned short u16x8 __attribute__((ext_vector_type(8)));
typedef unsigned short u16x4 __attribute__((ext_vector_type(4)));
typedef float f32x4 __attribute__((ext_vector_type(4)));
typedef unsigned short ushort_t;

// fp32 -> bf16 round-nearest-even
__device__ __forceinline__ ushort_t f2b(float f) {
  union { float f; unsigned u; } c; c.f = f;
  unsigned r = c.u + 0x7fffu + ((c.u >> 16) & 1u);
  return (ushort_t)(r >> 16);
}
__device__ __forceinline__ float b2f(ushort_t u) {
  union { float f; unsigned u; } c; c.u = ((unsigned)u) << 16;
  return c.f;
}

// gelu, tanh approximation (max abs dev from exact erf-gelu ~1e-3)
__device__ __forceinline__ float gelu_f(float x) {
  float y = 0.7978845608f * x * (1.0f + 0.044715f * x * x);
  float e = __expf(2.0f * y);
  float th = 1.0f - 2.0f / (e + 1.0f);   // tanh(y)
  return 0.5f * x * (1.0f + th);
}

__device__ __forceinline__ void gload16(const void* g, void* l) {
  __builtin_amdgcn_global_load_lds(
      (const __attribute__((address_space(1))) unsigned int*)g,
      (__attribute__((address_space(3))) unsigned int*)l, 16, 0, 0);
}

// DPP cross-lane move within 16-lane rows (VALU pipe, no LDS round-trip)
template <int CTRL>
__device__ __forceinline__ float dppmv(float x) {
  union { float f; int i; } c; c.f = x;
  c.i = __builtin_amdgcn_update_dpp(c.i, c.i, CTRL, 0xF, 0xF, true);
  return c.f;
}
__device__ __forceinline__ float redmax16(float x) {
  x = fmaxf(x, dppmv<0xB1>(x));
  x = fmaxf(x, dppmv<0x4E>(x));
  x = fmaxf(x, dppmv<0x124>(x));
  x = fmaxf(x, dppmv<0x128>(x));
  return x;
}
__device__ __forceinline__ float redsum16(float x) {
  x += dppmv<0xB1>(x);
  x += dppmv<0x4E>(x);
  x += dppmv<0x124>(x);
  x += dppmv<0x128>(x);
  return x;
}

// ---------------- embedding: bf16 x out, u16x4 vectorized ----------------
__global__ __launch_bounds__(256) void embed_kernel(
    const float* __restrict__ ids, const float* __restrict__ w,
    const float* __restrict__ bvec, ushort_t* __restrict__ x) {
  int idx = blockIdx.x * 256 + threadIdx.x;           // group of 4 channels
  if (idx >= (int)(XSZ / 4)) return;
  int bs = idx / (H / 4);
  int hc = (idx % (H / 4)) * 4;
  f32x4 s = *(const f32x4*)&bvec[hc];
  #pragma unroll
  for (int k = 0; k < 4; ++k) {
    float id = ids[bs * 4 + k];
    f32x4 wv = *(const f32x4*)&w[k * H + hc];
    #pragma unroll
    for (int j = 0; j < 4; ++j) s[j] += id * wv[j];
  }
  u16x4 pk;
  #pragma unroll
  for (int j = 0; j < 4; ++j) pk[j] = f2b(s[j]);
  *(u16x4*)&x[(size_t)bs * H + hc] = pk;
}

// ---------------- layernorm: wave-per-row, u16x4 vectorized ----------------
__global__ __launch_bounds__(256) void ln_kernel(
    const ushort_t* __restrict__ x, const float* __restrict__ g,
    const float* __restrict__ bvec, ushort_t* __restrict__ out) {
  const int wave = threadIdx.x >> 6, lane = threadIdx.x & 63;
  const int row = blockIdx.x * 4 + wave;
  const ushort_t* xr = x + (size_t)row * H;
  float v[12];
  #pragma unroll
  for (int j = 0; j < 3; ++j) {
    u16x4 a = *(const u16x4*)&xr[lane * 4 + j * 256];
    #pragma unroll
    for (int q = 0; q < 4; ++q) v[j * 4 + q] = b2f(a[q]);
  }
  float s = 0.f, ss = 0.f;
  #pragma unroll
  for (int i = 0; i < 12; ++i) { s += v[i]; ss += v[i] * v[i]; }
  for (int off = 1; off < 64; off <<= 1) {
    s  += __shfl_xor(s,  off);
    ss += __shfl_xor(ss, off);
  }
  float mean = s * (1.0f / H);
  float var  = ss * (1.0f / H) - mean * mean;
  float rstd = rsqrtf(var + 1e-12f);
  ushort_t* orow = out + (size_t)row * H;
  #pragma unroll
  for (int j = 0; j < 3; ++j) {
    f32x4 gv = *(const f32x4*)&g[lane * 4 + j * 256];
    f32x4 bv = *(const f32x4*)&bvec[lane * 4 + j * 256];
    u16x4 pk;
    #pragma unroll
    for (int q = 0; q < 4; ++q)
      pk[q] = f2b((v[j * 4 + q] - mean) * rstd * gv[q] + bv[q]);
    *(u16x4*)&orow[lane * 4 + j * 256] = pk;
  }
}

// ---------------- weight transpose + fp32->bf16 ----------------
__global__ __launch_bounds__(256) void tcvt_kernel(
    const float* __restrict__ in, ushort_t* __restrict__ out,
    int K, int N, size_t inZ, size_t outZ) {
  __shared__ float tile[32][33];
  const float* inz = in + blockIdx.z * inZ;
  ushort_t* outz = out + blockIdx.z * outZ;
  int k0 = blockIdx.y * 32, n0 = blockIdx.x * 32;
  int tx = threadIdx.x & 31, ty = threadIdx.x >> 5;
  #pragma unroll
  for (int i = 0; i < 4; ++i) {
    int kk = ty + i * 8;
    tile[kk][tx] = inz[(size_t)(k0 + kk) * N + n0 + tx];
  }
  __syncthreads();
  #pragma unroll
  for (int i = 0; i < 4; ++i) {
    int nn = ty + i * 8;
    outz[(size_t)(n0 + nn) * K + k0 + tx] = f2b(tile[tx][nn]);
  }
}

__global__ __launch_bounds__(256) void concat_bias_kernel(
    const float* __restrict__ bq, const float* __restrict__ bk,
    const float* __restrict__ bv, float* __restrict__ out) {
  int i = blockIdx.x * 256 + threadIdx.x;
  if (i >= L * QKV_N) return;
  int l = i / QKV_N, c = i % QKV_N;
  float val = (c < H) ? bq[l * H + c] : (c < 2 * H) ? bk[l * H + c - H] : bv[l * H + c - 2 * H];
  out[i] = val;
}

// ============================================================================
// 128 x BN bf16 MFMA GEMM: 2 LDS buffers (depth-1 prefetch), single barrier
// per K-step, unroll-by-2 for immediate LDS offsets. N-FASTEST tile order.
// LDS 48 KB (BN=256) -> 3 blocks/CU BY LDS; launch_bounds min-waves kept at
// 2/SIMD so the register allocator is NOT constrained (round-17 lesson:
// forcing 3 waves/SIMD spilled acc -> 750 MB scratch writes, 2.4x slowdown).
// Occupancy comes from actual usage: VGPR ~128 allows 4 waves/SIMD, LDS
// allows 3 blocks/CU -> 3 blocks resident; capacity 768 fits FFN1 (768)
// and QKV (576) in one round.
// ============================================================================
// EPI: 0 = bias -> bf16 (+ vT for bn>=1536), 1 = bias + residual(bf16) -> bf16,
//      2 = bias + gelu -> bf16
template <int BN, int EPI>
__global__ __launch_bounds__(256, (BN == 256 ? 2 : 3)) void bgemm(
    const ushort_t* __restrict__ A, const ushort_t* __restrict__ Wt,
    const float* __restrict__ bias, const ushort_t* __restrict__ res,
    ushort_t* __restrict__ Cb, ushort_t* __restrict__ Cv,
    int M, int N, int K, int ncol) {
  constexpr int LDSB = (128 + BN) * 32;   // elems per buffer
  constexpr int NLD  = (128 + BN) / 64;   // gload sweeps per thread per K-tile
  constexpr int NI   = BN / 32;           // B-fragments per wave
  __shared__ ushort_t lds[2 * LDSB];

  // T1: bijective XCD swizzle (m204), N-fastest tile mapping
  const int nwg = (int)gridDim.x;
  const int qq = nwg >> 3, r0 = nwg & 7;
  const int xcd = (int)blockIdx.x & 7, loc = (int)blockIdx.x >> 3;
  const int swz = (xcd < r0 ? xcd * (qq + 1) : r0 * (qq + 1) + (xcd - r0) * qq) + loc;
  const int bm = (swz / ncol) * 128, bn = (swz % ncol) * BN;

  const int t = threadIdx.x;
  const int wid = t >> 6, lane = t & 63;
  const int fcol = lane & 15, fgrp = lane >> 4;
  const int wm = wid >> 1, wn = wid & 1;

  const ushort_t* src[NLD];
  int dst[NLD];
  #pragma unroll
  for (int j = 0; j < NLD; ++j) {
    int idx = j * 2048 + t * 8;
    dst[j] = idx;
    int ch = (idx >> 3) & 3;
    int row;
    const ushort_t* base;
    if (idx < 4096) { row = idx >> 5;           base = A  + (size_t)(bm + row) * K; }
    else            { row = (idx - 4096) >> 5;  base = Wt + (size_t)(bn + row) * K; }
    src[j] = base + ((ch ^ ((row >> 1) & 3)) << 3);
  }

  int aoff[4], boff[NI];
  #pragma unroll
  for (int mi = 0; mi < 4; ++mi) {
    int row = wm * 64 + mi * 16 + fcol;
    aoff[mi] = row * 32 + ((fgrp ^ ((row >> 1) & 3)) << 3);
  }
  #pragma unroll
  for (int ni = 0; ni < NI; ++ni) {
    int row = wn * (BN / 2) + ni * 16 + fcol;
    boff[ni] = 4096 + row * 32 + ((fgrp ^ ((row >> 1) & 3)) << 3);
  }

  f32x4 acc[4][NI] = {};

  // prologue: tile 0 -> buf0
  #pragma unroll
  for (int j = 0; j < NLD; ++j) gload16(src[j], &lds[dst[j]]);
  int kgl = 32;

// STEP(P, DOSTAGE): wait tile P landed -> barrier (also orders prior reads
// of buf[P^1] before this step's stage into it) -> stage tile tau+1 ->
// ds_read buf[P] -> MFMA.
#define GEMM_STEP(P, DOSTAGE)                                              \
  {                                                                        \
    asm volatile("s_waitcnt vmcnt(0)" ::: "memory");                       \
    __builtin_amdgcn_sched_barrier(0);                                     \
    __builtin_amdgcn_s_barrier();                                          \
    __builtin_amdgcn_sched_barrier(0);                                     \
    if (DOSTAGE) {                                                         \
      _Pragma("unroll")                                                    \
      for (int j = 0; j < NLD; ++j)                                        \
        gload16(src[j] + kgl, &lds[((P) ^ 1) * LDSB + dst[j]]);            \
      kgl += 32;                                                           \
    }                                                                      \
    bf16x8 af[4], bfr[NI];                                                 \
    _Pragma("unroll")                                                      \
    for (int mi = 0; mi < 4; ++mi)                                         \
      af[mi] = *(const bf16x8*)&lds[(P) * LDSB + aoff[mi]];                \
    _Pragma("unroll")                                                      \
    for (int ni = 0; ni < NI; ++ni)                                        \
      bfr[ni] = *(const bf16x8*)&lds[(P) * LDSB + boff[ni]];               \
    __builtin_amdgcn_s_setprio(1);                                         \
    _Pragma("unroll")                                                      \
    for (int mi = 0; mi < 4; ++mi)                                         \
      _Pragma("unroll")                                                    \
      for (int ni = 0; ni < NI; ++ni)                                      \
        acc[mi][ni] = __builtin_amdgcn_mfma_f32_16x16x32_bf16(             \
            af[mi], bfr[ni], acc[mi][ni], 0, 0, 0);                        \
    __builtin_amdgcn_s_setprio(0);                                         \
  }

  const int NT = K >> 5;   // 24 or 96, even
  for (int tau = 0; tau < NT - 2; tau += 2) {
    GEMM_STEP(0, true)
    GEMM_STEP(1, true)
  }
  GEMM_STEP(0, true)    // tau = NT-2: stages tile NT-1 -> buf1
  GEMM_STEP(1, false)   // tau = NT-1
#undef GEMM_STEP

  // epilogue (m = ..+fgrp*4+r, n = ..+fcol)
  if (EPI == 0 && bn >= 2 * H) {
    // V block-columns -> transposed vT[c][m], 8-B packed stores (m-quad)
    #pragma unroll
    for (int mi = 0; mi < 4; ++mi) {
      const int m = bm + wm * 64 + mi * 16 + fgrp * 4;
      #pragma unroll
      for (int ni = 0; ni < NI; ++ni) {
        const int n = bn + wn * (BN / 2) + ni * 16 + fcol;
        const float bb = bias[n];
        u16x4 pk;
        #pragma unroll
        for (int r = 0; r < 4; ++r) pk[r] = f2b(acc[mi][ni][r] + bb);
        *(u16x4*)&Cv[(size_t)(n - 2 * H) * M + m] = pk;
      }
    }
    return;
  }
  #pragma unroll
  for (int mi = 0; mi < 4; ++mi) {
    const int m = bm + wm * 64 + mi * 16 + fgrp * 4;
    #pragma unroll
    for (int ni = 0; ni < NI; ++ni) {
      const int n = bn + wn * (BN / 2) + ni * 16 + fcol;
      const float bb = bias[n];
      #pragma unroll
      for (int r = 0; r < 4; ++r) {
        float val = acc[mi][ni][r] + bb;
        if (EPI == 1) {
          val += b2f(res[(size_t)(m + r) * N + n]);
          Cb[(size_t)(m + r) * N + n] = f2b(val);
        } else if (EPI == 2) {
          Cb[(size_t)(m + r) * N + n] = f2b(gelu_f(val));
        } else {
          Cb[(size_t)(m + r) * N + n] = f2b(val);
        }
      }
    }
  }
}

// ---------------- BigBird sparse attention, bf16 MFMA flash-style -----------
__global__ __launch_bounds__(256) void attn_mfma(
    const ushort_t* __restrict__ qkv, const ushort_t* __restrict__ vT,
    const int* __restrict__ rb, ushort_t* __restrict__ ao) {
  __shared__ ushort_t Ks[2][64 * 72];
  __shared__ ushort_t Vt[2][64 * 72];
  __shared__ ushort_t Ps[4][16 * 72];
  const int xb = blockIdx.x;
  const int n = ((xb & 7) << 3) | (xb >> 3);   // bijective on 0..63
  const int hh = blockIdx.y, b = blockIdx.z;
  const int t = threadIdx.x;
  const int wid = t >> 6, lane = t & 63;
  const int fcol = lane & 15, fgrp = lane >> 4;
  const int qr0 = n * 64 + wid * 16;

  bf16x8 qf[2];
  #pragma unroll
  for (int kc = 0; kc < 2; ++kc)
    qf[kc] = *(const bf16x8*)&qkv[((size_t)(b * S) + qr0 + fcol) * QKV_N + hh * 64 + kc * 32 + fgrp * 8];

  f32x4 oacc[4] = {};
  float mrow[4], lrow[4];
  #pragma unroll
  for (int r = 0; r < 4; ++r) { mrow[r] = -1e30f; lrow[r] = 0.f; }

  int kbs[AB];
  kbs[0] = (n > 0) ? n - 1 : 0;
  kbs[1] = n;
  kbs[2] = (n < NB - 1) ? n + 1 : NB - 1;
  kbs[3] = 0;
  kbs[4] = NB - 1;
  kbs[5] = rb[n * R + 0];
  kbs[6] = rb[n * R + 1];
  kbs[7] = rb[n * R + 2];

  const ushort_t* kbase = qkv + (size_t)(b * S) * QKV_N + H + hh * 64;
  const ushort_t* vbase = vT + (size_t)(hh * 64) * ROWS + b * S;

  const int srow = t >> 3;
  const int soff = (t & 7) * 8;

  {
    const int kb = kbs[0];
    u16x8 k0 = *(const u16x8*)&kbase[(size_t)(kb * 64 + srow) * QKV_N + soff];
    u16x8 k1 = *(const u16x8*)&kbase[(size_t)(kb * 64 + srow + 32) * QKV_N + soff];
    u16x8 v0 = *(const u16x8*)&vbase[(size_t)srow * ROWS + kb * 64 + soff];
    u16x8 v1 = *(const u16x8*)&vbase[(size_t)(srow + 32) * ROWS + kb * 64 + soff];
    *(u16x8*)&Ks[0][srow * 72 + soff]        = k0;
    *(u16x8*)&Ks[0][(srow + 32) * 72 + soff] = k1;
    *(u16x8*)&Vt[0][srow * 72 + soff]        = v0;
    *(u16x8*)&Vt[0][(srow + 32) * 72 + soff] = v1;
  }
  __syncthreads();

  for (int a = 0; a < AB; ++a) {
    const int buf = a & 1;

    u16x8 pk0, pk1, pv0, pv1;
    if (a + 1 < AB) {
      const int kb = kbs[a + 1];
      pk0 = *(const u16x8*)&kbase[(size_t)(kb * 64 + srow) * QKV_N + soff];
      pk1 = *(const u16x8*)&kbase[(size_t)(kb * 64 + srow + 32) * QKV_N + soff];
      pv0 = *(const u16x8*)&vbase[(size_t)srow * ROWS + kb * 64 + soff];
      pv1 = *(const u16x8*)&vbase[(size_t)(srow + 32) * ROWS + kb * 64 + soff];
    }

    f32x4 sacc[4] = {};
    __builtin_amdgcn_s_setprio(1);
    #pragma unroll
    for (int ni = 0; ni < 4; ++ni)
      #pragma unroll
      for (int kc = 0; kc < 2; ++kc) {
        bf16x8 kf = *(const bf16x8*)&Ks[buf][(ni * 16 + fcol) * 72 + kc * 32 + fgrp * 8];
        sacc[ni] = __builtin_amdgcn_mfma_f32_16x16x32_bf16(qf[kc], kf, sacc[ni], 0, 0, 0);
      }
    __builtin_amdgcn_s_setprio(0);

    // online softmax: DPP 16-lane reduces
    #pragma unroll
    for (int ni = 0; ni < 4; ++ni)
      #pragma unroll
      for (int r = 0; r < 4; ++r) sacc[ni][r] *= SCALE;
    #pragma unroll
    for (int r = 0; r < 4; ++r) {
      float tm = fmaxf(fmaxf(sacc[0][r], sacc[1][r]), fmaxf(sacc[2][r], sacc[3][r]));
      tm = redmax16(tm);
      float mn = fmaxf(mrow[r], tm);
      float corr = __expf(mrow[r] - mn);
      mrow[r] = mn;
      float rs = 0.f;
      #pragma unroll
      for (int ni = 0; ni < 4; ++ni) {
        float p = __expf(sacc[ni][r] - mn);
        sacc[ni][r] = p;
        rs += p;
      }
      rs = redsum16(rs);
      lrow[r] = lrow[r] * corr + rs;
      #pragma unroll
      for (int ni = 0; ni < 4; ++ni) oacc[ni][r] *= corr;
    }

    if (a + 1 < AB) {
      *(u16x8*)&Ks[buf ^ 1][srow * 72 + soff]        = pk0;
      *(u16x8*)&Ks[buf ^ 1][(srow + 32) * 72 + soff] = pk1;
      *(u16x8*)&Vt[buf ^ 1][srow * 72 + soff]        = pv0;
      *(u16x8*)&Vt[buf ^ 1][(srow + 32) * 72 + soff] = pv1;
    }

    #pragma unroll
    for (int ni = 0; ni < 4; ++ni)
      #pragma unroll
      for (int r = 0; r < 4; ++r)
        Ps[wid][(fgrp * 4 + r) * 72 + ni * 16 + fcol] = f2b(sacc[ni][r]);

    bf16x8 pa[2];
    #pragma unroll
    for (int kc = 0; kc < 2; ++kc)
      pa[kc] = *(const bf16x8*)&Ps[wid][fcol * 72 + kc * 32 + fgrp * 8];

    __builtin_amdgcn_s_setprio(1);
    #pragma unroll
    for (int kc = 0; kc < 2; ++kc)
      #pragma unroll
      for (int ni = 0; ni < 4; ++ni) {
        bf16x8 vb = *(const bf16x8*)&Vt[buf][(ni * 16 + fcol) * 72 + kc * 32 + fgrp * 8];
        oacc[ni] = __builtin_amdgcn_mfma_f32_16x16x32_bf16(pa[kc], vb, oacc[ni], 0, 0, 0);
      }
    __builtin_amdgcn_s_setprio(0);

    __syncthreads();
  }

  #pragma unroll
  for (int r = 0; r < 4; ++r) {
    float inv = 1.0f / lrow[r];
    int row = qr0 + fgrp * 4 + r;
    #pragma unroll
    for (int ni = 0; ni < 4; ++ni)
      ao[((size_t)(b * S) + row) * H + hh * 64 + ni * 16 + fcol] = f2b(oacc[ni][r] * inv);
  }
}

// ---------------- classifier: bf16 x in, vectorized ----------------
__global__ __launch_bounds__(64) void clf_kernel(
    const ushort_t* __restrict__ x, const float* __restrict__ w,
    const float* __restrict__ bvec, float* __restrict__ out) {
  int row = blockIdx.x;
  int lane = threadIdx.x;
  const ushort_t* xr = x + (size_t)row * H;
  f32x4 p = {0.f, 0.f, 0.f, 0.f};
  #pragma unroll
  for (int j = 0; j < 3; ++j) {
    u16x4 xv4 = *(const u16x4*)&xr[lane * 4 + j * 256];
    #pragma unroll
    for (int q = 0; q < 4; ++q) {
      float xv = b2f(xv4[q]);
      f32x4 wv = *(const f32x4*)&w[(lane * 4 + j * 256 + q) * 4];
      #pragma unroll
      for (int c = 0; c < 4; ++c) p[c] += xv * wv[c];
    }
  }
  #pragma unroll
  for (int c = 0; c < 4; ++c)
    for (int off = 1; off < 64; off <<= 1) p[c] += __shfl_xor(p[c], off);
  if (lane == 0) {
    float l0 = p[0] + bvec[0], l1 = p[1] + bvec[1], l2 = p[2] + bvec[2], l3 = p[3] + bvec[3];
    float mx = fmaxf(fmaxf(l0, l1), fmaxf(l2, l3));
    float e0 = __expf(l0 - mx), e1 = __expf(l1 - mx), e2 = __expf(l2 - mx), e3 = __expf(l3 - mx);
    float inv = 1.0f / (e0 + e1 + e2 + e3);
    out[row * 4 + 0] = e0 * inv;
    out[row * 4 + 1] = e1 * inv;
    out[row * 4 + 2] = e2 * inv;
    out[row * 4 + 3] = e3 * inv;
  }
}

// ---------------- driver ----------------
extern "C" void kernel_launch(void* const* d_in, const int* in_sizes, int n_in,
                              void* d_out, int out_size, void* d_ws, size_t ws_size,
                              hipStream_t stream) {
  const float* input_ids = (const float*)d_in[0];
  const int*   rand_bl   = (const int*)  d_in[1];
  const float* emb_w = (const float*)d_in[2];
  const float* emb_b = (const float*)d_in[3];
  const float* ln1_g = (const float*)d_in[4];
  const float* ln1_b = (const float*)d_in[5];
  const float* wq = (const float*)d_in[6];
  const float* bq = (const float*)d_in[7];
  const float* wk = (const float*)d_in[8];
  const float* bk = (const float*)d_in[9];
  const float* wv = (const float*)d_in[10];
  const float* bv = (const float*)d_in[11];
  const float* wo = (const float*)d_in[12];
  const float* bo = (const float*)d_in[13];
  const float* ln2_g = (const float*)d_in[14];
  const float* ln2_b = (const float*)d_in[15];
  const float* w1 = (const float*)d_in[16];
  const float* b1 = (const float*)d_in[17];
  const float* w2 = (const float*)d_in[18];
  const float* b2 = (const float*)d_in[19];
  const float* clf_w = (const float*)d_in[20];
  const float* clf_b = (const float*)d_in[21];

  char* p = (char*)d_ws;
  ushort_t* x    = (ushort_t*)p; p += XSZ * 2;           // bf16 residual stream
  ushort_t* h    = (ushort_t*)p; p += XSZ * 2;
  ushort_t* qkv  = (ushort_t*)p; p += (size_t)ROWS * QKV_N * 2;
  ushort_t* ao   = (ushort_t*)p; p += XSZ * 2;
  ushort_t* ff   = qkv;  // [ROWS][FF] aliases qkv+ao (dead when FFN runs)
  ushort_t* vT   = (ushort_t*)p; p += (size_t)H * ROWS * 2;   // V^T [H][ROWS]
  ushort_t* qkvT = (ushort_t*)p; p += (size_t)L * QKV_N * H * 2;
  ushort_t* woT  = (ushort_t*)p; p += (size_t)L * H * H * 2;
  ushort_t* w1T  = (ushort_t*)p; p += (size_t)L * H * FF * 2;
  ushort_t* w2T  = (ushort_t*)p; p += (size_t)L * FF * H * 2;
  float*    bqkv = (float*)p;    p += (size_t)L * QKV_N * 4;

  // ---- weight prep ----
  tcvt_kernel<<<dim3(H / 32, H / 32, L), 256, 0, stream>>>(
      wq, qkvT + 0 * H * H, H, H, (size_t)H * H, (size_t)QKV_N * H);
  tcvt_kernel<<<dim3(H / 32, H / 32, L), 256, 0, stream>>>(
      wk, qkvT + 1 * H * H, H, H, (size_t)H * H, (size_t)QKV_N * H);
  tcvt_kernel<<<dim3(H / 32, H / 32, L), 256, 0, stream>>>(
      wv, qkvT + 2 * H * H, H, H, (size_t)H * H, (size_t)QKV_N * H);
  tcvt_kernel<<<dim3(H / 32, H / 32, L), 256, 0, stream>>>(
      wo, woT, H, H, (size_t)H * H, (size_t)H * H);
  tcvt_kernel<<<dim3(FF / 32, H / 32, L), 256, 0, stream>>>(
      w1, w1T, H, FF, (size_t)H * FF, (size_t)H * FF);
  tcvt_kernel<<<dim3(H / 32, FF / 32, L), 256, 0, stream>>>(
      w2, w2T, FF, H, (size_t)FF * H, (size_t)FF * H);
  concat_bias_kernel<<<(L * QKV_N + 255) / 256, 256, 0, stream>>>(bq, bk, bv, bqkv);

  embed_kernel<<<(int)((XSZ / 4 + 255) / 256), 256, 0, stream>>>(input_ids, emb_w, emb_b, x);

  for (int l = 0; l < L; ++l) {
    ln_kernel<<<ROWS / 4, 256, 0, stream>>>(x, ln1_g + l * H, ln1_b + l * H, h);

    // QKV: M=8192, N=2304, K=768 -> BN=256, grid 576 (3/CU -> one round)
    bgemm<256, 0><<<(ROWS / 128) * (QKV_N / 256), 256, 0, stream>>>(
        h, qkvT + (size_t)l * QKV_N * H, bqkv + l * QKV_N, nullptr,
        qkv, vT, ROWS, QKV_N, H, QKV_N / 256);

    attn_mfma<<<dim3(NB, NH, B), 256, 0, stream>>>(qkv, vT, rand_bl, ao);

    // O-proj: M=8192, N=768, K=768 -> BN=128, grid 384, residual bf16
    bgemm<128, 1><<<(ROWS / 128) * (H / 128), 256, 0, stream>>>(
        ao, woT + (size_t)l * H * H, bo + l * H, x, x, nullptr, ROWS, H, H, H / 128);

    ln_kernel<<<ROWS / 4, 256, 0, stream>>>(x, ln2_g + l * H, ln2_b + l * H, h);

    // FFN1: M=8192, N=3072, K=768 -> BN=256, grid 768 (3/CU -> one round)
    bgemm<256, 2><<<(ROWS / 128) * (FF / 256), 256, 0, stream>>>(
        h, w1T + (size_t)l * H * FF, b1 + l * FF, nullptr,
        ff, nullptr, ROWS, FF, H, FF / 256);

    // FFN2: M=8192, N=768, K=3072 -> BN=128, grid 384, residual bf16
    bgemm<128, 1><<<(ROWS / 128) * (H / 128), 256, 0, stream>>>(
        ff, w2T + (size_t)l * FF * H, b2 + l * H, x, x, nullptr, ROWS, H, FF, H / 128);
  }

  clf_kernel<<<ROWS, 64, 0, stream>>>(x, clf_w, clf_b, (float*)d_out);
}

// Round 19
// 924.729 us; speedup vs baseline: 2.4258x; 1.0205x over previous
//
#include <hip/hip_runtime.h>
#include <math.h>

// ---------------- problem constants ----------------
constexpr int B  = 2;
constexpr int S  = 4096;
constexpr int H  = 768;
constexpr int NH = 12;
constexpr int FF = 3072;
constexpr int L  = 4;
constexpr int R  = 3;
constexpr int NB = 64;
constexpr int AB = 8;            // 3 window + 2 global + 3 random
constexpr float SCALE = 0.125f;  // 1/sqrt(64)
constexpr int QKV_N = 3 * H;     // 2304

constexpr int ROWS = B * S;                  // 8192
constexpr size_t XSZ = (size_t)B * S * H;    // 6291456

typedef short bf16x8 __attribute__((ext_vector_type(8)));
typedef unsigned short u16x8 __attribute__((ext_vector_type(8)));
typedef unsigned short u16x4 __attribute__((ext_vector_type(4)));
typedef float f32x4 __attribute__((ext_vector_type(4)));
typedef unsigned short ushort_t;

// fp32 -> bf16 round-nearest-even
__device__ __forceinline__ ushort_t f2b(float f) {
  union { float f; unsigned u; } c; c.f = f;
  unsigned r = c.u + 0x7fffu + ((c.u >> 16) & 1u);
  return (ushort_t)(r >> 16);
}
__device__ __forceinline__ float b2f(ushort_t u) {
  union { float f; unsigned u; } c; c.u = ((unsigned)u) << 16;
  return c.f;
}

// gelu, tanh approximation (max abs dev from exact erf-gelu ~1e-3)
__device__ __forceinline__ float gelu_f(float x) {
  float y = 0.7978845608f * x * (1.0f + 0.044715f * x * x);
  float e = __expf(2.0f * y);
  float th = 1.0f - 2.0f / (e + 1.0f);   // tanh(y)
  return 0.5f * x * (1.0f + th);
}

__device__ __forceinline__ void gload16(const void* g, void* l) {
  __builtin_amdgcn_global_load_lds(
      (const __attribute__((address_space(1))) unsigned int*)g,
      (__attribute__((address_space(3))) unsigned int*)l, 16, 0, 0);
}

template <int N>
__device__ __forceinline__ void waitvm() {
  if constexpr (N == 0)      { asm volatile("s_waitcnt vmcnt(0)" ::: "memory"); }
  else if constexpr (N == 4) { asm volatile("s_waitcnt vmcnt(4)" ::: "memory"); }
  else if constexpr (N == 6) { asm volatile("s_waitcnt vmcnt(6)" ::: "memory"); }
  else                       { asm volatile("s_waitcnt vmcnt(8)" ::: "memory"); }
}

// DPP cross-lane move within 16-lane rows (VALU pipe, no LDS round-trip)
template <int CTRL>
__device__ __forceinline__ float dppmv(float x) {
  union { float f; int i; } c; c.f = x;
  c.i = __builtin_amdgcn_update_dpp(c.i, c.i, CTRL, 0xF, 0xF, true);
  return c.f;
}
__device__ __forceinline__ float redmax16(float x) {
  x = fmaxf(x, dppmv<0xB1>(x));
  x = fmaxf(x, dppmv<0x4E>(x));
  x = fmaxf(x, dppmv<0x124>(x));
  x = fmaxf(x, dppmv<0x128>(x));
  return x;
}
__device__ __forceinline__ float redsum16(float x) {
  x += dppmv<0xB1>(x);
  x += dppmv<0x4E>(x);
  x += dppmv<0x124>(x);
  x += dppmv<0x128>(x);
  return x;
}

// ---------------- embedding: bf16 x out, u16x4 vectorized ----------------
__global__ __launch_bounds__(256) void embed_kernel(
    const float* __restrict__ ids, const float* __restrict__ w,
    const float* __restrict__ bvec, ushort_t* __restrict__ x) {
  int idx = blockIdx.x * 256 + threadIdx.x;           // group of 4 channels
  if (idx >= (int)(XSZ / 4)) return;
  int bs = idx / (H / 4);
  int hc = (idx % (H / 4)) * 4;
  f32x4 s = *(const f32x4*)&bvec[hc];
  #pragma unroll
  for (int k = 0; k < 4; ++k) {
    float id = ids[bs * 4 + k];
    f32x4 wv = *(const f32x4*)&w[k * H + hc];
    #pragma unroll
    for (int j = 0; j < 4; ++j) s[j] += id * wv[j];
  }
  u16x4 pk;
  #pragma unroll
  for (int j = 0; j < 4; ++j) pk[j] = f2b(s[j]);
  *(u16x4*)&x[(size_t)bs * H + hc] = pk;
}

// ---------------- layernorm: wave-per-row, u16x4 vectorized ----------------
__global__ __launch_bounds__(256) void ln_kernel(
    const ushort_t* __restrict__ x, const float* __restrict__ g,
    const float* __restrict__ bvec, ushort_t* __restrict__ out) {
  const int wave = threadIdx.x >> 6, lane = threadIdx.x & 63;
  const int row = blockIdx.x * 4 + wave;
  const ushort_t* xr = x + (size_t)row * H;
  float v[12];
  #pragma unroll
  for (int j = 0; j < 3; ++j) {
    u16x4 a = *(const u16x4*)&xr[lane * 4 + j * 256];
    #pragma unroll
    for (int q = 0; q < 4; ++q) v[j * 4 + q] = b2f(a[q]);
  }
  float s = 0.f, ss = 0.f;
  #pragma unroll
  for (int i = 0; i < 12; ++i) { s += v[i]; ss += v[i] * v[i]; }
  for (int off = 1; off < 64; off <<= 1) {
    s  += __shfl_xor(s,  off);
    ss += __shfl_xor(ss, off);
  }
  float mean = s * (1.0f / H);
  float var  = ss * (1.0f / H) - mean * mean;
  float rstd = rsqrtf(var + 1e-12f);
  ushort_t* orow = out + (size_t)row * H;
  #pragma unroll
  for (int j = 0; j < 3; ++j) {
    f32x4 gv = *(const f32x4*)&g[lane * 4 + j * 256];
    f32x4 bv = *(const f32x4*)&bvec[lane * 4 + j * 256];
    u16x4 pk;
    #pragma unroll
    for (int q = 0; q < 4; ++q)
      pk[q] = f2b((v[j * 4 + q] - mean) * rstd * gv[q] + bv[q]);
    *(u16x4*)&orow[lane * 4 + j * 256] = pk;
  }
}

// ---------------- weight transpose + fp32->bf16 ----------------
__global__ __launch_bounds__(256) void tcvt_kernel(
    const float* __restrict__ in, ushort_t* __restrict__ out,
    int K, int N, size_t inZ, size_t outZ) {
  __shared__ float tile[32][33];
  const float* inz = in + blockIdx.z * inZ;
  ushort_t* outz = out + blockIdx.z * outZ;
  int k0 = blockIdx.y * 32, n0 = blockIdx.x * 32;
  int tx = threadIdx.x & 31, ty = threadIdx.x >> 5;
  #pragma unroll
  for (int i = 0; i < 4; ++i) {
    int kk = ty + i * 8;
    tile[kk][tx] = inz[(size_t)(k0 + kk) * N + n0 + tx];
  }
  __syncthreads();
  #pragma unroll
  for (int i = 0; i < 4; ++i) {
    int nn = ty + i * 8;
    outz[(size_t)(n0 + nn) * K + k0 + tx] = f2b(tile[tx][nn]);
  }
}

__global__ __launch_bounds__(256) void concat_bias_kernel(
    const float* __restrict__ bq, const float* __restrict__ bk,
    const float* __restrict__ bv, float* __restrict__ out) {
  int i = blockIdx.x * 256 + threadIdx.x;
  if (i >= L * QKV_N) return;
  int l = i / QKV_N, c = i % QKV_N;
  float val = (c < H) ? bq[l * H + c] : (c < 2 * H) ? bk[l * H + c - H] : bv[l * H + c - 2 * H];
  out[i] = val;
}

// ============================================================================
// 128 x BN bf16 MFMA GEMM (round-16 champion): 3 LDS buffers, depth-2
// prefetch, single barrier per K-step, unroll-by-3 for immediate LDS
// offsets, vmcnt(NLD) counted wait, N-fastest tile order + XCD swizzle.
// launch_bounds min-waves 2 (BN=256) / 3 (BN=128): does NOT constrain the
// register allocator (forcing 3/SIMD at BN=256 spilled acc, round 17).
// A/B evidence r16 vs r18: depth-2 prefetch > depth-1 + extra occupancy.
// ============================================================================
// EPI: 0 = bias -> bf16 (+ vT for bn>=1536), 1 = bias + residual(bf16) -> bf16,
//      2 = bias + gelu -> bf16
template <int BN, int EPI>
__global__ __launch_bounds__(256, (BN == 256 ? 2 : 3)) void bgemm(
    const ushort_t* __restrict__ A, const ushort_t* __restrict__ Wt,
    const float* __restrict__ bias, const ushort_t* __restrict__ res,
    ushort_t* __restrict__ Cb, ushort_t* __restrict__ Cv,
    int M, int N, int K, int ncol) {
  constexpr int LDSB = (128 + BN) * 32;   // elems per buffer
  constexpr int NLD  = (128 + BN) / 64;   // gload sweeps per thread per K-tile
  constexpr int NI   = BN / 32;           // B-fragments per wave
  __shared__ ushort_t lds[3 * LDSB];

  // T1: bijective XCD swizzle (m204), N-fastest tile mapping
  const int nwg = (int)gridDim.x;
  const int qq = nwg >> 3, r0 = nwg & 7;
  const int xcd = (int)blockIdx.x & 7, loc = (int)blockIdx.x >> 3;
  const int swz = (xcd < r0 ? xcd * (qq + 1) : r0 * (qq + 1) + (xcd - r0) * qq) + loc;
  const int bm = (swz / ncol) * 128, bn = (swz % ncol) * BN;

  const int t = threadIdx.x;
  const int wid = t >> 6, lane = t & 63;
  const int fcol = lane & 15, fgrp = lane >> 4;
  const int wm = wid >> 1, wn = wid & 1;

  const ushort_t* src[NLD];
  int dst[NLD];
  #pragma unroll
  for (int j = 0; j < NLD; ++j) {
    int idx = j * 2048 + t * 8;
    dst[j] = idx;
    int ch = (idx >> 3) & 3;
    int row;
    const ushort_t* base;
    if (idx < 4096) { row = idx >> 5;           base = A  + (size_t)(bm + row) * K; }
    else            { row = (idx - 4096) >> 5;  base = Wt + (size_t)(bn + row) * K; }
    src[j] = base + ((ch ^ ((row >> 1) & 3)) << 3);
  }

  int aoff[4], boff[NI];
  #pragma unroll
  for (int mi = 0; mi < 4; ++mi) {
    int row = wm * 64 + mi * 16 + fcol;
    aoff[mi] = row * 32 + ((fgrp ^ ((row >> 1) & 3)) << 3);
  }
  #pragma unroll
  for (int ni = 0; ni < NI; ++ni) {
    int row = wn * (BN / 2) + ni * 16 + fcol;
    boff[ni] = 4096 + row * 32 + ((fgrp ^ ((row >> 1) & 3)) << 3);
  }

  f32x4 acc[4][NI] = {};

  #pragma unroll
  for (int j = 0; j < NLD; ++j) gload16(src[j], &lds[dst[j]]);
  #pragma unroll
  for (int j = 0; j < NLD; ++j) gload16(src[j] + 32, &lds[LDSB + dst[j]]);
  int kgl = 64;

#define GEMM_STEP(P, DOSTAGE, WN)                                          \
  {                                                                        \
    waitvm<WN>();                                                          \
    __builtin_amdgcn_sched_barrier(0);                                     \
    __builtin_amdgcn_s_barrier();                                          \
    __builtin_amdgcn_sched_barrier(0);                                     \
    if (DOSTAGE) {                                                         \
      _Pragma("unroll")                                                    \
      for (int j = 0; j < NLD; ++j)                                        \
        gload16(src[j] + kgl, &lds[(((P) + 2) % 3) * LDSB + dst[j]]);      \
      kgl += 32;                                                           \
    }                                                                      \
    bf16x8 af[4], bfr[NI];                                                 \
    _Pragma("unroll")                                                      \
    for (int mi = 0; mi < 4; ++mi)                                         \
      af[mi] = *(const bf16x8*)&lds[(P) * LDSB + aoff[mi]];                \
    _Pragma("unroll")                                                      \
    for (int ni = 0; ni < NI; ++ni)                                        \
      bfr[ni] = *(const bf16x8*)&lds[(P) * LDSB + boff[ni]];               \
    __builtin_amdgcn_s_setprio(1);                                         \
    _Pragma("unroll")                                                      \
    for (int mi = 0; mi < 4; ++mi)                                         \
      _Pragma("unroll")                                                    \
      for (int ni = 0; ni < NI; ++ni)                                      \
        acc[mi][ni] = __builtin_amdgcn_mfma_f32_16x16x32_bf16(             \
            af[mi], bfr[ni], acc[mi][ni], 0, 0, 0);                        \
    __builtin_amdgcn_s_setprio(0);                                         \
  }

  const int NT = K >> 5;   // 24 or 96, divisible by 3
  for (int tau = 0; tau < NT - 3; tau += 3) {
    GEMM_STEP(0, true, NLD)
    GEMM_STEP(1, true, NLD)
    GEMM_STEP(2, true, NLD)
  }
  GEMM_STEP(0, true,  NLD)
  GEMM_STEP(1, false, NLD)
  GEMM_STEP(2, false, 0)
#undef GEMM_STEP

  // epilogue (m = ..+fgrp*4+r, n = ..+fcol)
  if (EPI == 0 && bn >= 2 * H) {
    // V block-columns -> transposed vT[c][m], 8-B packed stores (m-quad)
    #pragma unroll
    for (int mi = 0; mi < 4; ++mi) {
      const int m = bm + wm * 64 + mi * 16 + fgrp * 4;
      #pragma unroll
      for (int ni = 0; ni < NI; ++ni) {
        const int n = bn + wn * (BN / 2) + ni * 16 + fcol;
        const float bb = bias[n];
        u16x4 pk;
        #pragma unroll
        for (int r = 0; r < 4; ++r) pk[r] = f2b(acc[mi][ni][r] + bb);
        *(u16x4*)&Cv[(size_t)(n - 2 * H) * M + m] = pk;
      }
    }
    return;
  }
  #pragma unroll
  for (int mi = 0; mi < 4; ++mi) {
    const int m = bm + wm * 64 + mi * 16 + fgrp * 4;
    #pragma unroll
    for (int ni = 0; ni < NI; ++ni) {
      const int n = bn + wn * (BN / 2) + ni * 16 + fcol;
      const float bb = bias[n];
      #pragma unroll
      for (int r = 0; r < 4; ++r) {
        float val = acc[mi][ni][r] + bb;
        if (EPI == 1) {
          val += b2f(res[(size_t)(m + r) * N + n]);
          Cb[(size_t)(m + r) * N + n] = f2b(val);
        } else if (EPI == 2) {
          Cb[(size_t)(m + r) * N + n] = f2b(gelu_f(val));
        } else {
          Cb[(size_t)(m + r) * N + n] = f2b(val);
        }
      }
    }
  }
}

// ---------------- BigBird sparse attention, bf16 MFMA flash-style -----------
__global__ __launch_bounds__(256) void attn_mfma(
    const ushort_t* __restrict__ qkv, const ushort_t* __restrict__ vT,
    const int* __restrict__ rb, ushort_t* __restrict__ ao) {
  __shared__ ushort_t Ks[2][64 * 72];
  __shared__ ushort_t Vt[2][64 * 72];
  __shared__ ushort_t Ps[4][16 * 72];
  const int xb = blockIdx.x;
  const int n = ((xb & 7) << 3) | (xb >> 3);   // bijective on 0..63
  const int hh = blockIdx.y, b = blockIdx.z;
  const int t = threadIdx.x;
  const int wid = t >> 6, lane = t & 63;
  const int fcol = lane & 15, fgrp = lane >> 4;
  const int qr0 = n * 64 + wid * 16;

  bf16x8 qf[2];
  #pragma unroll
  for (int kc = 0; kc < 2; ++kc)
    qf[kc] = *(const bf16x8*)&qkv[((size_t)(b * S) + qr0 + fcol) * QKV_N + hh * 64 + kc * 32 + fgrp * 8];

  f32x4 oacc[4] = {};
  float mrow[4], lrow[4];
  #pragma unroll
  for (int r = 0; r < 4; ++r) { mrow[r] = -1e30f; lrow[r] = 0.f; }

  int kbs[AB];
  kbs[0] = (n > 0) ? n - 1 : 0;
  kbs[1] = n;
  kbs[2] = (n < NB - 1) ? n + 1 : NB - 1;
  kbs[3] = 0;
  kbs[4] = NB - 1;
  kbs[5] = rb[n * R + 0];
  kbs[6] = rb[n * R + 1];
  kbs[7] = rb[n * R + 2];

  const ushort_t* kbase = qkv + (size_t)(b * S) * QKV_N + H + hh * 64;
  const ushort_t* vbase = vT + (size_t)(hh * 64) * ROWS + b * S;

  const int srow = t >> 3;
  const int soff = (t & 7) * 8;

  {
    const int kb = kbs[0];
    u16x8 k0 = *(const u16x8*)&kbase[(size_t)(kb * 64 + srow) * QKV_N + soff];
    u16x8 k1 = *(const u16x8*)&kbase[(size_t)(kb * 64 + srow + 32) * QKV_N + soff];
    u16x8 v0 = *(const u16x8*)&vbase[(size_t)srow * ROWS + kb * 64 + soff];
    u16x8 v1 = *(const u16x8*)&vbase[(size_t)(srow + 32) * ROWS + kb * 64 + soff];
    *(u16x8*)&Ks[0][srow * 72 + soff]        = k0;
    *(u16x8*)&Ks[0][(srow + 32) * 72 + soff] = k1;
    *(u16x8*)&Vt[0][srow * 72 + soff]        = v0;
    *(u16x8*)&Vt[0][(srow + 32) * 72 + soff] = v1;
  }
  __syncthreads();

  for (int a = 0; a < AB; ++a) {
    const int buf = a & 1;

    u16x8 pk0, pk1, pv0, pv1;
    if (a + 1 < AB) {
      const int kb = kbs[a + 1];
      pk0 = *(const u16x8*)&kbase[(size_t)(kb * 64 + srow) * QKV_N + soff];
      pk1 = *(const u16x8*)&kbase[(size_t)(kb * 64 + srow + 32) * QKV_N + soff];
      pv0 = *(const u16x8*)&vbase[(size_t)srow * ROWS + kb * 64 + soff];
      pv1 = *(const u16x8*)&vbase[(size_t)(srow + 32) * ROWS + kb * 64 + soff];
    }

    f32x4 sacc[4] = {};
    __builtin_amdgcn_s_setprio(1);
    #pragma unroll
    for (int ni = 0; ni < 4; ++ni)
      #pragma unroll
      for (int kc = 0; kc < 2; ++kc) {
        bf16x8 kf = *(const bf16x8*)&Ks[buf][(ni * 16 + fcol) * 72 + kc * 32 + fgrp * 8];
        sacc[ni] = __builtin_amdgcn_mfma_f32_16x16x32_bf16(qf[kc], kf, sacc[ni], 0, 0, 0);
      }
    __builtin_amdgcn_s_setprio(0);

    // online softmax: DPP 16-lane reduces
    #pragma unroll
    for (int ni = 0; ni < 4; ++ni)
      #pragma unroll
      for (int r = 0; r < 4; ++r) sacc[ni][r] *= SCALE;
    #pragma unroll
    for (int r = 0; r < 4; ++r) {
      float tm = fmaxf(fmaxf(sacc[0][r], sacc[1][r]), fmaxf(sacc[2][r], sacc[3][r]));
      tm = redmax16(tm);
      float mn = fmaxf(mrow[r], tm);
      float corr = __expf(mrow[r] - mn);
      mrow[r] = mn;
      float rs = 0.f;
      #pragma unroll
      for (int ni = 0; ni < 4; ++ni) {
        float p = __expf(sacc[ni][r] - mn);
        sacc[ni][r] = p;
        rs += p;
      }
      rs = redsum16(rs);
      lrow[r] = lrow[r] * corr + rs;
      #pragma unroll
      for (int ni = 0; ni < 4; ++ni) oacc[ni][r] *= corr;
    }

    if (a + 1 < AB) {
      *(u16x8*)&Ks[buf ^ 1][srow * 72 + soff]        = pk0;
      *(u16x8*)&Ks[buf ^ 1][(srow + 32) * 72 + soff] = pk1;
      *(u16x8*)&Vt[buf ^ 1][srow * 72 + soff]        = pv0;
      *(u16x8*)&Vt[buf ^ 1][(srow + 32) * 72 + soff] = pv1;
    }

    #pragma unroll
    for (int ni = 0; ni < 4; ++ni)
      #pragma unroll
      for (int r = 0; r < 4; ++r)
        Ps[wid][(fgrp * 4 + r) * 72 + ni * 16 + fcol] = f2b(sacc[ni][r]);

    bf16x8 pa[2];
    #pragma unroll
    for (int kc = 0; kc < 2; ++kc)
      pa[kc] = *(const bf16x8*)&Ps[wid][fcol * 72 + kc * 32 + fgrp * 8];

    __builtin_amdgcn_s_setprio(1);
    #pragma unroll
    for (int kc = 0; kc < 2; ++kc)
      #pragma unroll
      for (int ni = 0; ni < 4; ++ni) {
        bf16x8 vb = *(const bf16x8*)&Vt[buf][(ni * 16 + fcol) * 72 + kc * 32 + fgrp * 8];
        oacc[ni] = __builtin_amdgcn_mfma_f32_16x16x32_bf16(pa[kc], vb, oacc[ni], 0, 0, 0);
      }
    __builtin_amdgcn_s_setprio(0);

    __syncthreads();
  }

  #pragma unroll
  for (int r = 0; r < 4; ++r) {
    float inv = 1.0f / lrow[r];
    int row = qr0 + fgrp * 4 + r;
    #pragma unroll
    for (int ni = 0; ni < 4; ++ni)
      ao[((size_t)(b * S) + row) * H + hh * 64 + ni * 16 + fcol] = f2b(oacc[ni][r] * inv);
  }
}

// ---------------- classifier: bf16 x in, vectorized ----------------
__global__ __launch_bounds__(64) void clf_kernel(
    const ushort_t* __restrict__ x, const float* __restrict__ w,
    const float* __restrict__ bvec, float* __restrict__ out) {
  int row = blockIdx.x;
  int lane = threadIdx.x;
  const ushort_t* xr = x + (size_t)row * H;
  f32x4 p = {0.f, 0.f, 0.f, 0.f};
  #pragma unroll
  for (int j = 0; j < 3; ++j) {
    u16x4 xv4 = *(const u16x4*)&xr[lane * 4 + j * 256];
    #pragma unroll
    for (int q = 0; q < 4; ++q) {
      float xv = b2f(xv4[q]);
      f32x4 wv = *(const f32x4*)&w[(lane * 4 + j * 256 + q) * 4];
      #pragma unroll
      for (int c = 0; c < 4; ++c) p[c] += xv * wv[c];
    }
  }
  #pragma unroll
  for (int c = 0; c < 4; ++c)
    for (int off = 1; off < 64; off <<= 1) p[c] += __shfl_xor(p[c], off);
  if (lane == 0) {
    float l0 = p[0] + bvec[0], l1 = p[1] + bvec[1], l2 = p[2] + bvec[2], l3 = p[3] + bvec[3];
    float mx = fmaxf(fmaxf(l0, l1), fmaxf(l2, l3));
    float e0 = __expf(l0 - mx), e1 = __expf(l1 - mx), e2 = __expf(l2 - mx), e3 = __expf(l3 - mx);
    float inv = 1.0f / (e0 + e1 + e2 + e3);
    out[row * 4 + 0] = e0 * inv;
    out[row * 4 + 1] = e1 * inv;
    out[row * 4 + 2] = e2 * inv;
    out[row * 4 + 3] = e3 * inv;
  }
}

// ---------------- driver ----------------
extern "C" void kernel_launch(void* const* d_in, const int* in_sizes, int n_in,
                              void* d_out, int out_size, void* d_ws, size_t ws_size,
                              hipStream_t stream) {
  const float* input_ids = (const float*)d_in[0];
  const int*   rand_bl   = (const int*)  d_in[1];
  const float* emb_w = (const float*)d_in[2];
  const float* emb_b = (const float*)d_in[3];
  const float* ln1_g = (const float*)d_in[4];
  const float* ln1_b = (const float*)d_in[5];
  const float* wq = (const float*)d_in[6];
  const float* bq = (const float*)d_in[7];
  const float* wk = (const float*)d_in[8];
  const float* bk = (const float*)d_in[9];
  const float* wv = (const float*)d_in[10];
  const float* bv = (const float*)d_in[11];
  const float* wo = (const float*)d_in[12];
  const float* bo = (const float*)d_in[13];
  const float* ln2_g = (const float*)d_in[14];
  const float* ln2_b = (const float*)d_in[15];
  const float* w1 = (const float*)d_in[16];
  const float* b1 = (const float*)d_in[17];
  const float* w2 = (const float*)d_in[18];
  const float* b2 = (const float*)d_in[19];
  const float* clf_w = (const float*)d_in[20];
  const float* clf_b = (const float*)d_in[21];

  char* p = (char*)d_ws;
  ushort_t* x    = (ushort_t*)p; p += XSZ * 2;           // bf16 residual stream
  ushort_t* h    = (ushort_t*)p; p += XSZ * 2;
  ushort_t* qkv  = (ushort_t*)p; p += (size_t)ROWS * QKV_N * 2;
  ushort_t* ao   = (ushort_t*)p; p += XSZ * 2;
  ushort_t* ff   = qkv;  // [ROWS][FF] aliases qkv+ao (dead when FFN runs)
  ushort_t* vT   = (ushort_t*)p; p += (size_t)H * ROWS * 2;   // V^T [H][ROWS]
  ushort_t* qkvT = (ushort_t*)p; p += (size_t)L * QKV_N * H * 2;
  ushort_t* woT  = (ushort_t*)p; p += (size_t)L * H * H * 2;
  ushort_t* w1T  = (ushort_t*)p; p += (size_t)L * H * FF * 2;
  ushort_t* w2T  = (ushort_t*)p; p += (size_t)L * FF * H * 2;
  float*    bqkv = (float*)p;    p += (size_t)L * QKV_N * 4;

  // ---- weight prep ----
  tcvt_kernel<<<dim3(H / 32, H / 32, L), 256, 0, stream>>>(
      wq, qkvT + 0 * H * H, H, H, (size_t)H * H, (size_t)QKV_N * H);
  tcvt_kernel<<<dim3(H / 32, H / 32, L), 256, 0, stream>>>(
      wk, qkvT + 1 * H * H, H, H, (size_t)H * H, (size_t)QKV_N * H);
  tcvt_kernel<<<dim3(H / 32, H / 32, L), 256, 0, stream>>>(
      wv, qkvT + 2 * H * H, H, H, (size_t)H * H, (size_t)QKV_N * H);
  tcvt_kernel<<<dim3(H / 32, H / 32, L), 256, 0, stream>>>(
      wo, woT, H, H, (size_t)H * H, (size_t)H * H);
  tcvt_kernel<<<dim3(FF / 32, H / 32, L), 256, 0, stream>>>(
      w1, w1T, H, FF, (size_t)H * FF, (size_t)H * FF);
  tcvt_kernel<<<dim3(H / 32, FF / 32, L), 256, 0, stream>>>(
      w2, w2T, FF, H, (size_t)FF * H, (size_t)FF * H);
  concat_bias_kernel<<<(L * QKV_N + 255) / 256, 256, 0, stream>>>(bq, bk, bv, bqkv);

  embed_kernel<<<(int)((XSZ / 4 + 255) / 256), 256, 0, stream>>>(input_ids, emb_w, emb_b, x);

  for (int l = 0; l < L; ++l) {
    ln_kernel<<<ROWS / 4, 256, 0, stream>>>(x, ln1_g + l * H, ln1_b + l * H, h);

    // QKV: M=8192, N=2304, K=768 -> BN=256, grid 576 (V part -> vT)
    bgemm<256, 0><<<(ROWS / 128) * (QKV_N / 256), 256, 0, stream>>>(
        h, qkvT + (size_t)l * QKV_N * H, bqkv + l * QKV_N, nullptr,
        qkv, vT, ROWS, QKV_N, H, QKV_N / 256);

    attn_mfma<<<dim3(NB, NH, B), 256, 0, stream>>>(qkv, vT, rand_bl, ao);

    // O-proj: M=8192, N=768, K=768 -> BN=128, grid 384, residual bf16
    bgemm<128, 1><<<(ROWS / 128) * (H / 128), 256, 0, stream>>>(
        ao, woT + (size_t)l * H * H, bo + l * H, x, x, nullptr, ROWS, H, H, H / 128);

    ln_kernel<<<ROWS / 4, 256, 0, stream>>>(x, ln2_g + l * H, ln2_b + l * H, h);

    // FFN1: M=8192, N=3072, K=768 -> BN=256, grid 768
    bgemm<256, 2><<<(ROWS / 128) * (FF / 256), 256, 0, stream>>>(
        h, w1T + (size_t)l * H * FF, b1 + l * FF, nullptr,
        ff, nullptr, ROWS, FF, H, FF / 256);

    // FFN2: M=8192, N=768, K=3072 -> BN=128, grid 384, residual bf16
    bgemm<128, 1><<<(ROWS / 128) * (H / 128), 256, 0, stream>>>(
        ff, w2T + (size_t)l * FF * H, b2 + l * H, x, x, nullptr, ROWS, H, FF, H / 128);
  }

  clf_kernel<<<ROWS, 64, 0, stream>>>(x, clf_w, clf_b, (float*)d_out);
}

// Round 20
// 922.907 us; speedup vs baseline: 2.4306x; 1.0020x over previous
//
#include <hip/hip_runtime.h>
#include <math.h>

// ---------------- problem constants ----------------
constexpr int B  = 2;
constexpr int S  = 4096;
constexpr int H  = 768;
constexpr int NH = 12;
constexpr int FF = 3072;
constexpr int L  = 4;
constexpr int R  = 3;
constexpr int NB = 64;
constexpr int AB = 8;            // 3 window + 2 global + 3 random
constexpr float SCALE = 0.125f;  // 1/sqrt(64)
constexpr int QKV_N = 3 * H;     // 2304

constexpr int ROWS = B * S;                  // 8192
constexpr size_t XSZ = (size_t)B * S * H;    // 6291456

typedef short bf16x8 __attribute__((ext_vector_type(8)));
typedef unsigned short u16x8 __attribute__((ext_vector_type(8)));
typedef unsigned short u16x4 __attribute__((ext_vector_type(4)));
typedef float f32x4 __attribute__((ext_vector_type(4)));
typedef unsigned short ushort_t;

// fp32 -> bf16 round-nearest-even
__device__ __forceinline__ ushort_t f2b(float f) {
  union { float f; unsigned u; } c; c.f = f;
  unsigned r = c.u + 0x7fffu + ((c.u >> 16) & 1u);
  return (ushort_t)(r >> 16);
}
__device__ __forceinline__ float b2f(ushort_t u) {
  union { float f; unsigned u; } c; c.u = ((unsigned)u) << 16;
  return c.f;
}

// gelu, tanh approximation (max abs dev from exact erf-gelu ~1e-3)
__device__ __forceinline__ float gelu_f(float x) {
  float y = 0.7978845608f * x * (1.0f + 0.044715f * x * x);
  float e = __expf(2.0f * y);
  float th = 1.0f - 2.0f / (e + 1.0f);   // tanh(y)
  return 0.5f * x * (1.0f + th);
}

__device__ __forceinline__ void gload16(const void* g, void* l) {
  __builtin_amdgcn_global_load_lds(
      (const __attribute__((address_space(1))) unsigned int*)g,
      (__attribute__((address_space(3))) unsigned int*)l, 16, 0, 0);
}

template <int N>
__device__ __forceinline__ void waitvm() {
  if constexpr (N == 0)      { asm volatile("s_waitcnt vmcnt(0)" ::: "memory"); }
  else if constexpr (N == 4) { asm volatile("s_waitcnt vmcnt(4)" ::: "memory"); }
  else if constexpr (N == 6) { asm volatile("s_waitcnt vmcnt(6)" ::: "memory"); }
  else                       { asm volatile("s_waitcnt vmcnt(8)" ::: "memory"); }
}

// DPP cross-lane move within 16-lane rows (VALU pipe, no LDS round-trip)
template <int CTRL>
__device__ __forceinline__ float dppmv(float x) {
  union { float f; int i; } c; c.f = x;
  c.i = __builtin_amdgcn_update_dpp(c.i, c.i, CTRL, 0xF, 0xF, true);
  return c.f;
}
__device__ __forceinline__ float redmax16(float x) {
  x = fmaxf(x, dppmv<0xB1>(x));
  x = fmaxf(x, dppmv<0x4E>(x));
  x = fmaxf(x, dppmv<0x124>(x));
  x = fmaxf(x, dppmv<0x128>(x));
  return x;
}
__device__ __forceinline__ float redsum16(float x) {
  x += dppmv<0xB1>(x);
  x += dppmv<0x4E>(x);
  x += dppmv<0x124>(x);
  x += dppmv<0x128>(x);
  return x;
}

// ---------------- embedding: bf16 x out, u16x4 vectorized ----------------
__global__ __launch_bounds__(256) void embed_kernel(
    const float* __restrict__ ids, const float* __restrict__ w,
    const float* __restrict__ bvec, ushort_t* __restrict__ x) {
  int idx = blockIdx.x * 256 + threadIdx.x;           // group of 4 channels
  if (idx >= (int)(XSZ / 4)) return;
  int bs = idx / (H / 4);
  int hc = (idx % (H / 4)) * 4;
  f32x4 s = *(const f32x4*)&bvec[hc];
  #pragma unroll
  for (int k = 0; k < 4; ++k) {
    float id = ids[bs * 4 + k];
    f32x4 wv = *(const f32x4*)&w[k * H + hc];
    #pragma unroll
    for (int j = 0; j < 4; ++j) s[j] += id * wv[j];
  }
  u16x4 pk;
  #pragma unroll
  for (int j = 0; j < 4; ++j) pk[j] = f2b(s[j]);
  *(u16x4*)&x[(size_t)bs * H + hc] = pk;
}

// ---------------- layernorm: wave-per-row, u16x4 vectorized ----------------
__global__ __launch_bounds__(256) void ln_kernel(
    const ushort_t* __restrict__ x, const float* __restrict__ g,
    const float* __restrict__ bvec, ushort_t* __restrict__ out) {
  const int wave = threadIdx.x >> 6, lane = threadIdx.x & 63;
  const int row = blockIdx.x * 4 + wave;
  const ushort_t* xr = x + (size_t)row * H;
  float v[12];
  #pragma unroll
  for (int j = 0; j < 3; ++j) {
    u16x4 a = *(const u16x4*)&xr[lane * 4 + j * 256];
    #pragma unroll
    for (int q = 0; q < 4; ++q) v[j * 4 + q] = b2f(a[q]);
  }
  float s = 0.f, ss = 0.f;
  #pragma unroll
  for (int i = 0; i < 12; ++i) { s += v[i]; ss += v[i] * v[i]; }
  for (int off = 1; off < 64; off <<= 1) {
    s  += __shfl_xor(s,  off);
    ss += __shfl_xor(ss, off);
  }
  float mean = s * (1.0f / H);
  float var  = ss * (1.0f / H) - mean * mean;
  float rstd = rsqrtf(var + 1e-12f);
  ushort_t* orow = out + (size_t)row * H;
  #pragma unroll
  for (int j = 0; j < 3; ++j) {
    f32x4 gv = *(const f32x4*)&g[lane * 4 + j * 256];
    f32x4 bv = *(const f32x4*)&bvec[lane * 4 + j * 256];
    u16x4 pk;
    #pragma unroll
    for (int q = 0; q < 4; ++q)
      pk[q] = f2b((v[j * 4 + q] - mean) * rstd * gv[q] + bv[q]);
    *(u16x4*)&orow[lane * 4 + j * 256] = pk;
  }
}

// ---------------- weight transpose + fp32->bf16 ----------------
__global__ __launch_bounds__(256) void tcvt_kernel(
    const float* __restrict__ in, ushort_t* __restrict__ out,
    int K, int N, size_t inZ, size_t outZ) {
  __shared__ float tile[32][33];
  const float* inz = in + blockIdx.z * inZ;
  ushort_t* outz = out + blockIdx.z * outZ;
  int k0 = blockIdx.y * 32, n0 = blockIdx.x * 32;
  int tx = threadIdx.x & 31, ty = threadIdx.x >> 5;
  #pragma unroll
  for (int i = 0; i < 4; ++i) {
    int kk = ty + i * 8;
    tile[kk][tx] = inz[(size_t)(k0 + kk) * N + n0 + tx];
  }
  __syncthreads();
  #pragma unroll
  for (int i = 0; i < 4; ++i) {
    int nn = ty + i * 8;
    outz[(size_t)(n0 + nn) * K + k0 + tx] = f2b(tile[tx][nn]);
  }
}

__global__ __launch_bounds__(256) void concat_bias_kernel(
    const float* __restrict__ bq, const float* __restrict__ bk,
    const float* __restrict__ bv, float* __restrict__ out) {
  int i = blockIdx.x * 256 + threadIdx.x;
  if (i >= L * QKV_N) return;
  int l = i / QKV_N, c = i % QKV_N;
  float val = (c < H) ? bq[l * H + c] : (c < 2 * H) ? bk[l * H + c - H] : bv[l * H + c - 2 * H];
  out[i] = val;
}

// ============================================================================
// 128 x BN bf16 MFMA GEMM (champion, r16/r19): 3 LDS buffers, depth-2
// prefetch, single barrier per K-step, unroll-by-3 for immediate LDS
// offsets, vmcnt(NLD) counted wait, N-fastest tile order + XCD swizzle.
// launch_bounds min-waves 2 (BN=256) / 3 (BN=128): does NOT constrain the
// register allocator (forcing 3/SIMD at BN=256 spilled acc, round 17).
// Measured argmax over: 2-barrier (r10), 8-phase 256^2 (r12), BM=64 (r5),
// M-fastest (r15), depth-1+occ (r18), occ-forced (r17) — all slower.
// ============================================================================
// EPI: 0 = bias -> bf16 (+ vT for bn>=1536), 1 = bias + residual(bf16) -> bf16,
//      2 = bias + gelu -> bf16
template <int BN, int EPI>
__global__ __launch_bounds__(256, (BN == 256 ? 2 : 3)) void bgemm(
    const ushort_t* __restrict__ A, const ushort_t* __restrict__ Wt,
    const float* __restrict__ bias, const ushort_t* __restrict__ res,
    ushort_t* __restrict__ Cb, ushort_t* __restrict__ Cv,
    int M, int N, int K, int ncol) {
  constexpr int LDSB = (128 + BN) * 32;   // elems per buffer
  constexpr int NLD  = (128 + BN) / 64;   // gload sweeps per thread per K-tile
  constexpr int NI   = BN / 32;           // B-fragments per wave
  __shared__ ushort_t lds[3 * LDSB];

  // T1: bijective XCD swizzle (m204), N-fastest tile mapping
  const int nwg = (int)gridDim.x;
  const int qq = nwg >> 3, r0 = nwg & 7;
  const int xcd = (int)blockIdx.x & 7, loc = (int)blockIdx.x >> 3;
  const int swz = (xcd < r0 ? xcd * (qq + 1) : r0 * (qq + 1) + (xcd - r0) * qq) + loc;
  const int bm = (swz / ncol) * 128, bn = (swz % ncol) * BN;

  const int t = threadIdx.x;
  const int wid = t >> 6, lane = t & 63;
  const int fcol = lane & 15, fgrp = lane >> 4;
  const int wm = wid >> 1, wn = wid & 1;

  const ushort_t* src[NLD];
  int dst[NLD];
  #pragma unroll
  for (int j = 0; j < NLD; ++j) {
    int idx = j * 2048 + t * 8;
    dst[j] = idx;
    int ch = (idx >> 3) & 3;
    int row;
    const ushort_t* base;
    if (idx < 4096) { row = idx >> 5;           base = A  + (size_t)(bm + row) * K; }
    else            { row = (idx - 4096) >> 5;  base = Wt + (size_t)(bn + row) * K; }
    src[j] = base + ((ch ^ ((row >> 1) & 3)) << 3);
  }

  int aoff[4], boff[NI];
  #pragma unroll
  for (int mi = 0; mi < 4; ++mi) {
    int row = wm * 64 + mi * 16 + fcol;
    aoff[mi] = row * 32 + ((fgrp ^ ((row >> 1) & 3)) << 3);
  }
  #pragma unroll
  for (int ni = 0; ni < NI; ++ni) {
    int row = wn * (BN / 2) + ni * 16 + fcol;
    boff[ni] = 4096 + row * 32 + ((fgrp ^ ((row >> 1) & 3)) << 3);
  }

  f32x4 acc[4][NI] = {};

  #pragma unroll
  for (int j = 0; j < NLD; ++j) gload16(src[j], &lds[dst[j]]);
  #pragma unroll
  for (int j = 0; j < NLD; ++j) gload16(src[j] + 32, &lds[LDSB + dst[j]]);
  int kgl = 64;

#define GEMM_STEP(P, DOSTAGE, WN)                                          \
  {                                                                        \
    waitvm<WN>();                                                          \
    __builtin_amdgcn_sched_barrier(0);                                     \
    __builtin_amdgcn_s_barrier();                                          \
    __builtin_amdgcn_sched_barrier(0);                                     \
    if (DOSTAGE) {                                                         \
      _Pragma("unroll")                                                    \
      for (int j = 0; j < NLD; ++j)                                        \
        gload16(src[j] + kgl, &lds[(((P) + 2) % 3) * LDSB + dst[j]]);      \
      kgl += 32;                                                           \
    }                                                                      \
    bf16x8 af[4], bfr[NI];                                                 \
    _Pragma("unroll")                                                      \
    for (int mi = 0; mi < 4; ++mi)                                         \
      af[mi] = *(const bf16x8*)&lds[(P) * LDSB + aoff[mi]];                \
    _Pragma("unroll")                                                      \
    for (int ni = 0; ni < NI; ++ni)                                        \
      bfr[ni] = *(const bf16x8*)&lds[(P) * LDSB + boff[ni]];               \
    __builtin_amdgcn_s_setprio(1);                                         \
    _Pragma("unroll")                                                      \
    for (int mi = 0; mi < 4; ++mi)                                         \
      _Pragma("unroll")                                                    \
      for (int ni = 0; ni < NI; ++ni)                                      \
        acc[mi][ni] = __builtin_amdgcn_mfma_f32_16x16x32_bf16(             \
            af[mi], bfr[ni], acc[mi][ni], 0, 0, 0);                        \
    __builtin_amdgcn_s_setprio(0);                                         \
  }

  const int NT = K >> 5;   // 24 or 96, divisible by 3
  for (int tau = 0; tau < NT - 3; tau += 3) {
    GEMM_STEP(0, true, NLD)
    GEMM_STEP(1, true, NLD)
    GEMM_STEP(2, true, NLD)
  }
  GEMM_STEP(0, true,  NLD)
  GEMM_STEP(1, false, NLD)
  GEMM_STEP(2, false, 0)
#undef GEMM_STEP

  // epilogue (m = ..+fgrp*4+r, n = ..+fcol)
  if (EPI == 0 && bn >= 2 * H) {
    // V block-columns -> transposed vT[c][m], 8-B packed stores (m-quad)
    #pragma unroll
    for (int mi = 0; mi < 4; ++mi) {
      const int m = bm + wm * 64 + mi * 16 + fgrp * 4;
      #pragma unroll
      for (int ni = 0; ni < NI; ++ni) {
        const int n = bn + wn * (BN / 2) + ni * 16 + fcol;
        const float bb = bias[n];
        u16x4 pk;
        #pragma unroll
        for (int r = 0; r < 4; ++r) pk[r] = f2b(acc[mi][ni][r] + bb);
        *(u16x4*)&Cv[(size_t)(n - 2 * H) * M + m] = pk;
      }
    }
    return;
  }
  #pragma unroll
  for (int mi = 0; mi < 4; ++mi) {
    const int m = bm + wm * 64 + mi * 16 + fgrp * 4;
    #pragma unroll
    for (int ni = 0; ni < NI; ++ni) {
      const int n = bn + wn * (BN / 2) + ni * 16 + fcol;
      const float bb = bias[n];
      #pragma unroll
      for (int r = 0; r < 4; ++r) {
        float val = acc[mi][ni][r] + bb;
        if (EPI == 1) {
          val += b2f(res[(size_t)(m + r) * N + n]);
          Cb[(size_t)(m + r) * N + n] = f2b(val);
        } else if (EPI == 2) {
          Cb[(size_t)(m + r) * N + n] = f2b(gelu_f(val));
        } else {
          Cb[(size_t)(m + r) * N + n] = f2b(val);
        }
      }
    }
  }
}

// ---------------- BigBird sparse attention, bf16 MFMA flash-style -----------
__global__ __launch_bounds__(256) void attn_mfma(
    const ushort_t* __restrict__ qkv, const ushort_t* __restrict__ vT,
    const int* __restrict__ rb, ushort_t* __restrict__ ao) {
  __shared__ ushort_t Ks[2][64 * 72];
  __shared__ ushort_t Vt[2][64 * 72];
  __shared__ ushort_t Ps[4][16 * 72];
  const int xb = blockIdx.x;
  const int n = ((xb & 7) << 3) | (xb >> 3);   // bijective on 0..63
  const int hh = blockIdx.y, b = blockIdx.z;
  const int t = threadIdx.x;
  const int wid = t >> 6, lane = t & 63;
  const int fcol = lane & 15, fgrp = lane >> 4;
  const int qr0 = n * 64 + wid * 16;

  bf16x8 qf[2];
  #pragma unroll
  for (int kc = 0; kc < 2; ++kc)
    qf[kc] = *(const bf16x8*)&qkv[((size_t)(b * S) + qr0 + fcol) * QKV_N + hh * 64 + kc * 32 + fgrp * 8];

  f32x4 oacc[4] = {};
  float mrow[4], lrow[4];
  #pragma unroll
  for (int r = 0; r < 4; ++r) { mrow[r] = -1e30f; lrow[r] = 0.f; }

  int kbs[AB];
  kbs[0] = (n > 0) ? n - 1 : 0;
  kbs[1] = n;
  kbs[2] = (n < NB - 1) ? n + 1 : NB - 1;
  kbs[3] = 0;
  kbs[4] = NB - 1;
  kbs[5] = rb[n * R + 0];
  kbs[6] = rb[n * R + 1];
  kbs[7] = rb[n * R + 2];

  const ushort_t* kbase = qkv + (size_t)(b * S) * QKV_N + H + hh * 64;
  const ushort_t* vbase = vT + (size_t)(hh * 64) * ROWS + b * S;

  const int srow = t >> 3;
  const int soff = (t & 7) * 8;

  {
    const int kb = kbs[0];
    u16x8 k0 = *(const u16x8*)&kbase[(size_t)(kb * 64 + srow) * QKV_N + soff];
    u16x8 k1 = *(const u16x8*)&kbase[(size_t)(kb * 64 + srow + 32) * QKV_N + soff];
    u16x8 v0 = *(const u16x8*)&vbase[(size_t)srow * ROWS + kb * 64 + soff];
    u16x8 v1 = *(const u16x8*)&vbase[(size_t)(srow + 32) * ROWS + kb * 64 + soff];
    *(u16x8*)&Ks[0][srow * 72 + soff]        = k0;
    *(u16x8*)&Ks[0][(srow + 32) * 72 + soff] = k1;
    *(u16x8*)&Vt[0][srow * 72 + soff]        = v0;
    *(u16x8*)&Vt[0][(srow + 32) * 72 + soff] = v1;
  }
  __syncthreads();

  for (int a = 0; a < AB; ++a) {
    const int buf = a & 1;

    u16x8 pk0, pk1, pv0, pv1;
    if (a + 1 < AB) {
      const int kb = kbs[a + 1];
      pk0 = *(const u16x8*)&kbase[(size_t)(kb * 64 + srow) * QKV_N + soff];
      pk1 = *(const u16x8*)&kbase[(size_t)(kb * 64 + srow + 32) * QKV_N + soff];
      pv0 = *(const u16x8*)&vbase[(size_t)srow * ROWS + kb * 64 + soff];
      pv1 = *(const u16x8*)&vbase[(size_t)(srow + 32) * ROWS + kb * 64 + soff];
    }

    f32x4 sacc[4] = {};
    __builtin_amdgcn_s_setprio(1);
    #pragma unroll
    for (int ni = 0; ni < 4; ++ni)
      #pragma unroll
      for (int kc = 0; kc < 2; ++kc) {
        bf16x8 kf = *(const bf16x8*)&Ks[buf][(ni * 16 + fcol) * 72 + kc * 32 + fgrp * 8];
        sacc[ni] = __builtin_amdgcn_mfma_f32_16x16x32_bf16(qf[kc], kf, sacc[ni], 0, 0, 0);
      }
    __builtin_amdgcn_s_setprio(0);

    // online softmax: DPP 16-lane reduces
    #pragma unroll
    for (int ni = 0; ni < 4; ++ni)
      #pragma unroll
      for (int r = 0; r < 4; ++r) sacc[ni][r] *= SCALE;
    #pragma unroll
    for (int r = 0; r < 4; ++r) {
      float tm = fmaxf(fmaxf(sacc[0][r], sacc[1][r]), fmaxf(sacc[2][r], sacc[3][r]));
      tm = redmax16(tm);
      float mn = fmaxf(mrow[r], tm);
      float corr = __expf(mrow[r] - mn);
      mrow[r] = mn;
      float rs = 0.f;
      #pragma unroll
      for (int ni = 0; ni < 4; ++ni) {
        float p = __expf(sacc[ni][r] - mn);
        sacc[ni][r] = p;
        rs += p;
      }
      rs = redsum16(rs);
      lrow[r] = lrow[r] * corr + rs;
      #pragma unroll
      for (int ni = 0; ni < 4; ++ni) oacc[ni][r] *= corr;
    }

    if (a + 1 < AB) {
      *(u16x8*)&Ks[buf ^ 1][srow * 72 + soff]        = pk0;
      *(u16x8*)&Ks[buf ^ 1][(srow + 32) * 72 + soff] = pk1;
      *(u16x8*)&Vt[buf ^ 1][srow * 72 + soff]        = pv0;
      *(u16x8*)&Vt[buf ^ 1][(srow + 32) * 72 + soff] = pv1;
    }

    #pragma unroll
    for (int ni = 0; ni < 4; ++ni)
      #pragma unroll
      for (int r = 0; r < 4; ++r)
        Ps[wid][(fgrp * 4 + r) * 72 + ni * 16 + fcol] = f2b(sacc[ni][r]);

    bf16x8 pa[2];
    #pragma unroll
    for (int kc = 0; kc < 2; ++kc)
      pa[kc] = *(const bf16x8*)&Ps[wid][fcol * 72 + kc * 32 + fgrp * 8];

    __builtin_amdgcn_s_setprio(1);
    #pragma unroll
    for (int kc = 0; kc < 2; ++kc)
      #pragma unroll
      for (int ni = 0; ni < 4; ++ni) {
        bf16x8 vb = *(const bf16x8*)&Vt[buf][(ni * 16 + fcol) * 72 + kc * 32 + fgrp * 8];
        oacc[ni] = __builtin_amdgcn_mfma_f32_16x16x32_bf16(pa[kc], vb, oacc[ni], 0, 0, 0);
      }
    __builtin_amdgcn_s_setprio(0);

    __syncthreads();
  }

  #pragma unroll
  for (int r = 0; r < 4; ++r) {
    float inv = 1.0f / lrow[r];
    int row = qr0 + fgrp * 4 + r;
    #pragma unroll
    for (int ni = 0; ni < 4; ++ni)
      ao[((size_t)(b * S) + row) * H + hh * 64 + ni * 16 + fcol] = f2b(oacc[ni][r] * inv);
  }
}

// ---------------- classifier: bf16 x in, vectorized ----------------
__global__ __launch_bounds__(64) void clf_kernel(
    const ushort_t* __restrict__ x, const float* __restrict__ w,
    const float* __restrict__ bvec, float* __restrict__ out) {
  int row = blockIdx.x;
  int lane = threadIdx.x;
  const ushort_t* xr = x + (size_t)row * H;
  f32x4 p = {0.f, 0.f, 0.f, 0.f};
  #pragma unroll
  for (int j = 0; j < 3; ++j) {
    u16x4 xv4 = *(const u16x4*)&xr[lane * 4 + j * 256];
    #pragma unroll
    for (int q = 0; q < 4; ++q) {
      float xv = b2f(xv4[q]);
      f32x4 wv = *(const f32x4*)&w[(lane * 4 + j * 256 + q) * 4];
      #pragma unroll
      for (int c = 0; c < 4; ++c) p[c] += xv * wv[c];
    }
  }
  #pragma unroll
  for (int c = 0; c < 4; ++c)
    for (int off = 1; off < 64; off <<= 1) p[c] += __shfl_xor(p[c], off);
  if (lane == 0) {
    float l0 = p[0] + bvec[0], l1 = p[1] + bvec[1], l2 = p[2] + bvec[2], l3 = p[3] + bvec[3];
    float mx = fmaxf(fmaxf(l0, l1), fmaxf(l2, l3));
    float e0 = __expf(l0 - mx), e1 = __expf(l1 - mx), e2 = __expf(l2 - mx), e3 = __expf(l3 - mx);
    float inv = 1.0f / (e0 + e1 + e2 + e3);
    out[row * 4 + 0] = e0 * inv;
    out[row * 4 + 1] = e1 * inv;
    out[row * 4 + 2] = e2 * inv;
    out[row * 4 + 3] = e3 * inv;
  }
}

// ---------------- driver ----------------
extern "C" void kernel_launch(void* const* d_in, const int* in_sizes, int n_in,
                              void* d_out, int out_size, void* d_ws, size_t ws_size,
                              hipStream_t stream) {
  const float* input_ids = (const float*)d_in[0];
  const int*   rand_bl   = (const int*)  d_in[1];
  const float* emb_w = (const float*)d_in[2];
  const float* emb_b = (const float*)d_in[3];
  const float* ln1_g = (const float*)d_in[4];
  const float* ln1_b = (const float*)d_in[5];
  const float* wq = (const float*)d_in[6];
  const float* bq = (const float*)d_in[7];
  const float* wk = (const float*)d_in[8];
  const float* bk = (const float*)d_in[9];
  const float* wv = (const float*)d_in[10];
  const float* bv = (const float*)d_in[11];
  const float* wo = (const float*)d_in[12];
  const float* bo = (const float*)d_in[13];
  const float* ln2_g = (const float*)d_in[14];
  const float* ln2_b = (const float*)d_in[15];
  const float* w1 = (const float*)d_in[16];
  const float* b1 = (const float*)d_in[17];
  const float* w2 = (const float*)d_in[18];
  const float* b2 = (const float*)d_in[19];
  const float* clf_w = (const float*)d_in[20];
  const float* clf_b = (const float*)d_in[21];

  char* p = (char*)d_ws;
  ushort_t* x    = (ushort_t*)p; p += XSZ * 2;           // bf16 residual stream
  ushort_t* h    = (ushort_t*)p; p += XSZ * 2;
  ushort_t* qkv  = (ushort_t*)p; p += (size_t)ROWS * QKV_N * 2;
  ushort_t* ao   = (ushort_t*)p; p += XSZ * 2;
  ushort_t* ff   = qkv;  // [ROWS][FF] aliases qkv+ao (dead when FFN runs)
  ushort_t* vT   = (ushort_t*)p; p += (size_t)H * ROWS * 2;   // V^T [H][ROWS]
  ushort_t* qkvT = (ushort_t*)p; p += (size_t)L * QKV_N * H * 2;
  ushort_t* woT  = (ushort_t*)p; p += (size_t)L * H * H * 2;
  ushort_t* w1T  = (ushort_t*)p; p += (size_t)L * H * FF * 2;
  ushort_t* w2T  = (ushort_t*)p; p += (size_t)L * FF * H * 2;
  float*    bqkv = (float*)p;    p += (size_t)L * QKV_N * 4;

  // ---- weight prep ----
  tcvt_kernel<<<dim3(H / 32, H / 32, L), 256, 0, stream>>>(
      wq, qkvT + 0 * H * H, H, H, (size_t)H * H, (size_t)QKV_N * H);
  tcvt_kernel<<<dim3(H / 32, H / 32, L), 256, 0, stream>>>(
      wk, qkvT + 1 * H * H, H, H, (size_t)H * H, (size_t)QKV_N * H);
  tcvt_kernel<<<dim3(H / 32, H / 32, L), 256, 0, stream>>>(
      wv, qkvT + 2 * H * H, H, H, (size_t)H * H, (size_t)QKV_N * H);
  tcvt_kernel<<<dim3(H / 32, H / 32, L), 256, 0, stream>>>(
      wo, woT, H, H, (size_t)H * H, (size_t)H * H);
  tcvt_kernel<<<dim3(FF / 32, H / 32, L), 256, 0, stream>>>(
      w1, w1T, H, FF, (size_t)H * FF, (size_t)H * FF);
  tcvt_kernel<<<dim3(H / 32, FF / 32, L), 256, 0, stream>>>(
      w2, w2T, FF, H, (size_t)FF * H, (size_t)FF * H);
  concat_bias_kernel<<<(L * QKV_N + 255) / 256, 256, 0, stream>>>(bq, bk, bv, bqkv);

  embed_kernel<<<(int)((XSZ / 4 + 255) / 256), 256, 0, stream>>>(input_ids, emb_w, emb_b, x);

  for (int l = 0; l < L; ++l) {
    ln_kernel<<<ROWS / 4, 256, 0, stream>>>(x, ln1_g + l * H, ln1_b + l * H, h);

    // QKV: M=8192, N=2304, K=768 -> BN=256, grid 576 (V part -> vT)
    bgemm<256, 0><<<(ROWS / 128) * (QKV_N / 256), 256, 0, stream>>>(
        h, qkvT + (size_t)l * QKV_N * H, bqkv + l * QKV_N, nullptr,
        qkv, vT, ROWS, QKV_N, H, QKV_N / 256);

    attn_mfma<<<dim3(NB, NH, B), 256, 0, stream>>>(qkv, vT, rand_bl, ao);

    // O-proj: M=8192, N=768, K=768 -> BN=128, grid 384, residual bf16
    bgemm<128, 1><<<(ROWS / 128) * (H / 128), 256, 0, stream>>>(
        ao, woT + (size_t)l * H * H, bo + l * H, x, x, nullptr, ROWS, H, H, H / 128);

    ln_kernel<<<ROWS / 4, 256, 0, stream>>>(x, ln2_g + l * H, ln2_b + l * H, h);

    // FFN1: M=8192, N=3072, K=768 -> BN=256, grid 768
    bgemm<256, 2><<<(ROWS / 128) * (FF / 256), 256, 0, stream>>>(
        h, w1T + (size_t)l * H * FF, b1 + l * FF, nullptr,
        ff, nullptr, ROWS, FF, H, FF / 256);

    // FFN2: M=8192, N=768, K=3072 -> BN=128, grid 384, residual bf16
    bgemm<128, 1><<<(ROWS / 128) * (H / 128), 256, 0, stream>>>(
        ff, w2T + (size_t)l * FF * H, b2 + l * H, x, x, nullptr, ROWS, H, FF, H / 128);
  }

  clf_kernel<<<ROWS, 64, 0, stream>>>(x, clf_w, clf_b, (float*)d_out);
}